// Round 1
// baseline (655.172 us; speedup 1.0000x reference)
//
#include <hip/hip_runtime.h>
#include <math.h>

// Shapes (fixed): B=2, Lq=1024, C=256, H=W=64 -> Lk=4096, NC=2, NH=8, D=32.
// Pipeline:
//   1. smean[b,c] = mean_l S_SM                       (mean_kernel, atomics)
//   2. sbias[b,o] = smean @ qp_W1[0:256] + qp_b1      (sbias_kernel)
//   3. fqT[b,l,c] = f_q[b,c,l]                        (transpose_fq)
//   4. h = relu(fqT @ qp_W1[256:512] + sbias) ; P_hat = h @ qp_W2 + qp_b2;
//      V = H(softmax(P_hat)) - H(softmax(P))          (gemm_qp, fused epilogue)
//   5. k = fqT@Wk+bk ; v = fqT@Wv+bv                  (gemm256<0>)
//   6. Qmid = relu([S_QP|S_SM]@phiQ_W1+b1); Q = Qmid@phiQ_W2+b2; q = Q@Wq+bq
//   7. flash attention w/ V-bias on logits            (attn_kernel)
//   8. N = ao@Wo+bo ; S_IC = S_SM - (N@phi_W+phi_b)   (gemm256<0>, gemm256<2>)

#define LQ 1024
#define HW 4096
#define CDIM 256

__device__ __forceinline__ void fma4(float4& a, float s, const float4& w) {
    a.x += s * w.x; a.y += s * w.y; a.z += s * w.z; a.w += s * w.w;
}

__device__ __forceinline__ float ent2(float a, float b) {
    float m  = fmaxf(a, b);
    float e0 = expf(a - m), e1 = expf(b - m);
    float iz = 1.f / (e0 + e1);
    float p0 = fmaxf(e0 * iz, 1e-8f);
    float p1 = fmaxf(e1 * iz, 1e-8f);
    return -(p0 * logf(p0) + p1 * logf(p1));
}

// ---- 1. mean over Lq (axis=1). grid 32 = B*16 slabs of 64 rows; atomic combine.
__global__ __launch_bounds__(256) void mean_kernel(const float* __restrict__ S_SM,
                                                   float* __restrict__ smean) {
    int bi = blockIdx.x;
    int b = bi >> 4, l0 = (bi & 15) * 64;
    int c = threadIdx.x;
    const float* p = S_SM + (size_t)b * LQ * CDIM + (size_t)l0 * CDIM + c;
    float acc = 0.f;
#pragma unroll 8
    for (int l = 0; l < 64; ++l) acc += p[(size_t)l * CDIM];
    atomicAdd(&smean[b * CDIM + c], acc * (1.f / 1024.f));
}

// ---- 2. sbias[b,o] = sum_c smean[b,c]*qp_W1[c,o] + qp_b1[o]
__global__ __launch_bounds__(256) void sbias_kernel(const float* __restrict__ smean,
                                                    const float* __restrict__ qpW1,
                                                    const float* __restrict__ qpb1,
                                                    float* __restrict__ sb) {
    __shared__ float s_s[CDIM];
    int b = blockIdx.x, o = threadIdx.x;
    s_s[o] = smean[b * CDIM + o];
    __syncthreads();
    float acc = qpb1[o];
    for (int c = 0; c < CDIM; ++c) acc += s_s[c] * qpW1[c * CDIM + o];
    sb[b * CDIM + o] = acc;
}

// ---- 3. transpose f_q [B,C,HW] -> fqT [B,HW,C]
__global__ __launch_bounds__(256) void transpose_fq(const float* __restrict__ f_q,
                                                    float* __restrict__ fqT) {
    __shared__ float tile[32][33];
    int b = blockIdx.z;
    int l0 = blockIdx.x * 32, c0 = blockIdx.y * 32;
    int tl = threadIdx.x & 31, tc = threadIdx.x >> 5;
#pragma unroll
    for (int r = 0; r < 4; ++r) {
        int c = c0 + tc + r * 8;
        tile[tc + r * 8][tl] = f_q[(size_t)b * CDIM * HW + (size_t)c * HW + l0 + tl];
    }
    __syncthreads();
    int tc2 = threadIdx.x & 31, tl2 = threadIdx.x >> 5;
#pragma unroll
    for (int r = 0; r < 4; ++r) {
        int l = l0 + tl2 + r * 8;
        fqT[(size_t)b * HW * CDIM + (size_t)l * CDIM + c0 + tc2] = tile[tc2][tl2 + r * 8];
    }
}

// ---- generic GEMM: out[M,256] = epi(A[M,K]@W[K,256] + bias)
// A rows are always length-256 (concat supplies A2 for k>=256).
// block = 256 thr; tile 16 rows x 256 cols; thread microtile 4 rows x 4 cols.
// EPI: 0 = none, 1 = relu, 2 = out = src2 - (acc+bias)
template <int EPI>
__global__ __launch_bounds__(256) void gemm256(const float* __restrict__ A1,
                                               const float* __restrict__ A2, int K,
                                               const float* __restrict__ W,
                                               const float* __restrict__ bias,
                                               const float* __restrict__ src2,
                                               float* __restrict__ out) {
    __shared__ float a_s[64][20];  // [kk][row], pad 20 keeps float4 reads aligned
    const int t = threadIdx.x;
    const int row0 = blockIdx.x * 16;
    const int p0 = (t >> 6) * 4;   // wave id * 4 rows
    const int o0 = (t & 63) * 4;   // column group
    float4 acc[4];
    acc[0] = acc[1] = acc[2] = acc[3] = float4{0.f, 0.f, 0.f, 0.f};
    for (int k0 = 0; k0 < K; k0 += 64) {
        const float* Asrc = (A2 != nullptr && k0 >= 256) ? A2 : A1;
        int kbase = (A2 != nullptr && k0 >= 256) ? (k0 - 256) : k0;
#pragma unroll
        for (int i = 0; i < 4; ++i) {
            int e = t + i * 256;
            a_s[e & 63][e >> 6] = Asrc[(size_t)(row0 + (e >> 6)) * 256 + kbase + (e & 63)];
        }
        __syncthreads();
#pragma unroll 8
        for (int kk = 0; kk < 64; ++kk) {
            float4 w = *(const float4*)&W[(size_t)(k0 + kk) * 256 + o0];
            float4 a = *(const float4*)&a_s[kk][p0];  // broadcast within wave
            fma4(acc[0], a.x, w);
            fma4(acc[1], a.y, w);
            fma4(acc[2], a.z, w);
            fma4(acc[3], a.w, w);
        }
        __syncthreads();
    }
    float4 bb = *(const float4*)&bias[o0];
#pragma unroll
    for (int i = 0; i < 4; ++i) {
        int row = row0 + p0 + i;
        float4 r = acc[i];
        r.x += bb.x; r.y += bb.y; r.z += bb.z; r.w += bb.w;
        if (EPI == 1) {
            r.x = fmaxf(r.x, 0.f); r.y = fmaxf(r.y, 0.f);
            r.z = fmaxf(r.z, 0.f); r.w = fmaxf(r.w, 0.f);
        }
        if (EPI == 2) {
            float4 s2 = *(const float4*)&src2[(size_t)row * 256 + o0];
            r.x = s2.x - r.x; r.y = s2.y - r.y; r.z = s2.z - r.z; r.w = s2.w - r.w;
        }
        *(float4*)&out[(size_t)row * 256 + o0] = r;
    }
}

// ---- 4. qp conv GEMM with fused P_hat / entropy / V epilogue.
// h tile lives in registers; each wave owns 4 full rows -> 64-lane shuffle
// reduce for the [256 -> 2] projection.
__global__ __launch_bounds__(256) void gemm_qp(const float* __restrict__ fqT,
                                               const float* __restrict__ W1lo,
                                               const float* __restrict__ sb,
                                               const float* __restrict__ qpW2,
                                               const float* __restrict__ qpb2,
                                               const float* __restrict__ P,
                                               float* __restrict__ outPhat,
                                               float* __restrict__ outV,
                                               float* __restrict__ Vw) {
    __shared__ float a_s[64][20];
    const int t = threadIdx.x;
    const int row0 = blockIdx.x * 16;
    const int p0 = (t >> 6) * 4;
    const int o0 = (t & 63) * 4;
    float4 acc[4];
    acc[0] = acc[1] = acc[2] = acc[3] = float4{0.f, 0.f, 0.f, 0.f};
    for (int k0 = 0; k0 < 256; k0 += 64) {
#pragma unroll
        for (int i = 0; i < 4; ++i) {
            int e = t + i * 256;
            a_s[e & 63][e >> 6] = fqT[(size_t)(row0 + (e >> 6)) * 256 + k0 + (e & 63)];
        }
        __syncthreads();
#pragma unroll 8
        for (int kk = 0; kk < 64; ++kk) {
            float4 w = *(const float4*)&W1lo[(size_t)(k0 + kk) * 256 + o0];
            float4 a = *(const float4*)&a_s[kk][p0];
            fma4(acc[0], a.x, w);
            fma4(acc[1], a.y, w);
            fma4(acc[2], a.z, w);
            fma4(acc[3], a.w, w);
        }
        __syncthreads();
    }
    const int brow = row0 >> 12;  // row0 / 4096 (batch)
    float4 bb = *(const float4*)&sb[brow * 256 + o0];
    float w20[4], w21[4];
#pragma unroll
    for (int j = 0; j < 4; ++j) {
        w20[j] = qpW2[(o0 + j) * 2];
        w21[j] = qpW2[(o0 + j) * 2 + 1];
    }
    float c0[4], c1[4];
#pragma unroll
    for (int i = 0; i < 4; ++i) {
        float h0 = fmaxf(((const float*)&acc[i])[0] + bb.x, 0.f);
        float h1 = fmaxf(((const float*)&acc[i])[1] + bb.y, 0.f);
        float h2 = fmaxf(((const float*)&acc[i])[2] + bb.z, 0.f);
        float h3 = fmaxf(((const float*)&acc[i])[3] + bb.w, 0.f);
        c0[i] = h0 * w20[0] + h1 * w20[1] + h2 * w20[2] + h3 * w20[3];
        c1[i] = h0 * w21[0] + h1 * w21[1] + h2 * w21[2] + h3 * w21[3];
    }
#pragma unroll
    for (int m = 1; m < 64; m <<= 1) {
#pragma unroll
        for (int i = 0; i < 4; ++i) {
            c0[i] += __shfl_xor(c0[i], m);
            c1[i] += __shfl_xor(c1[i], m);
        }
    }
    if ((t & 63) == 0) {
        float b20 = qpb2[0], b21 = qpb2[1];
#pragma unroll
        for (int i = 0; i < 4; ++i) {
            int row = row0 + p0 + i;
            int hw = row & 4095, b = row >> 12;
            float ph0 = c0[i] + b20, ph1 = c1[i] + b21;
            float Vv = ent2(ph0, ph1) -
                       ent2(P[(size_t)b * 8192 + hw], P[(size_t)b * 8192 + 4096 + hw]);
            outPhat[(size_t)b * 8192 + hw] = ph0;
            outPhat[(size_t)b * 8192 + 4096 + hw] = ph1;
            outV[b * 4096 + hw] = Vv;
            Vw[b * 4096 + hw] = Vv;
        }
    }
}

// ---- 7. flash attention. 1 block = (b, h, 64-query tile); kv chunks of 64.
// logits = q.k/sqrt(32) + V[kv]; online softmax; O accum in regs.
__global__ __launch_bounds__(256) void attn_kernel(const float* __restrict__ qmat,
                                                   const float* __restrict__ kmat,
                                                   const float* __restrict__ vmat,
                                                   const float* __restrict__ Vw,
                                                   float* __restrict__ ao) {
    __shared__ float q_s[64][36];
    __shared__ float k_s[64][36];
    __shared__ float v_s[64][36];
    __shared__ float p_s[64][68];
    __shared__ float m_st[64], l_st[64], al_st[64], vb_s[64];
    const int t = threadIdx.x;
    const int blk = blockIdx.x;
    const int qt = blk & 15, h = (blk >> 4) & 7, b = blk >> 7;
    const int q0 = qt * 64;
    const float* qbase = qmat + ((size_t)b * LQ + q0) * CDIM + h * 32;
    const float* kbase = kmat + (size_t)b * HW * CDIM + h * 32;
    const float* vbase = vmat + (size_t)b * HW * CDIM + h * 32;
#pragma unroll
    for (int i = 0; i < 2; ++i) {
        int e = t + i * 256, r = e >> 3, dv = e & 7;
        *(float4*)&q_s[r][dv * 4] = *(const float4*)&qbase[(size_t)r * CDIM + dv * 4];
    }
    if (t < 64) { m_st[t] = -INFINITY; l_st[t] = 0.f; }
    const int rg = t >> 4, cg = t & 15;
    const int qi0 = rg * 4, j0 = cg * 4;
    const int qa = (t >> 3) * 2, qb2 = qa + 1, d0 = (t & 7) * 4;
    float oa[4] = {0.f, 0.f, 0.f, 0.f}, ob[4] = {0.f, 0.f, 0.f, 0.f};
    const float rsq = 0.17677669529663687f;  // 1/sqrt(32)
    __syncthreads();
    for (int kv0 = 0; kv0 < HW; kv0 += 64) {
#pragma unroll
        for (int i = 0; i < 2; ++i) {
            int e = t + i * 256, r = e >> 3, dv = e & 7;
            *(float4*)&k_s[r][dv * 4] =
                *(const float4*)&kbase[(size_t)(kv0 + r) * CDIM + dv * 4];
            *(float4*)&v_s[r][dv * 4] =
                *(const float4*)&vbase[(size_t)(kv0 + r) * CDIM + dv * 4];
        }
        if (t < 64) vb_s[t] = Vw[(size_t)b * HW + kv0 + t];
        __syncthreads();
        // S = q.k^T for 4x4 microtile
        float s[4][4] = {};
#pragma unroll
        for (int dv = 0; dv < 8; ++dv) {
            float4 q4[4], k4[4];
#pragma unroll
            for (int i = 0; i < 4; ++i) q4[i] = *(const float4*)&q_s[qi0 + i][dv * 4];
#pragma unroll
            for (int j = 0; j < 4; ++j) k4[j] = *(const float4*)&k_s[j0 + j][dv * 4];
#pragma unroll
            for (int i = 0; i < 4; ++i)
#pragma unroll
                for (int j = 0; j < 4; ++j)
                    s[i][j] += q4[i].x * k4[j].x + q4[i].y * k4[j].y +
                               q4[i].z * k4[j].z + q4[i].w * k4[j].w;
        }
#pragma unroll
        for (int i = 0; i < 4; ++i)
#pragma unroll
            for (int j = 0; j < 4; ++j) s[i][j] = s[i][j] * rsq + vb_s[j0 + j];
        // online softmax; row qi spans 16 contiguous lanes within the wave
#pragma unroll
        for (int i = 0; i < 4; ++i) {
            float rm = fmaxf(fmaxf(s[i][0], s[i][1]), fmaxf(s[i][2], s[i][3]));
#pragma unroll
            for (int m = 1; m < 16; m <<= 1) rm = fmaxf(rm, __shfl_xor(rm, m));
            float mo = m_st[qi0 + i];
            float mn = fmaxf(mo, rm);
            float al = expf(mo - mn);
            float e0 = expf(s[i][0] - mn), e1 = expf(s[i][1] - mn);
            float e2 = expf(s[i][2] - mn), e3 = expf(s[i][3] - mn);
            float rs = e0 + e1 + e2 + e3;
#pragma unroll
            for (int m = 1; m < 16; m <<= 1) rs += __shfl_xor(rs, m);
            float4 pw = {e0, e1, e2, e3};
            *(float4*)&p_s[qi0 + i][j0] = pw;
            if (cg == 0) {  // same wave as readers; lockstep-safe
                m_st[qi0 + i] = mn;
                l_st[qi0 + i] = al * l_st[qi0 + i] + rs;
                al_st[qi0 + i] = al;
            }
        }
        __syncthreads();
        // PV: thread owns 2 rows x 4 d-cols
        float ala = al_st[qa], alb = al_st[qb2];
#pragma unroll
        for (int d = 0; d < 4; ++d) { oa[d] *= ala; ob[d] *= alb; }
#pragma unroll 4
        for (int j4 = 0; j4 < 16; ++j4) {
            float4 pa = *(const float4*)&p_s[qa][j4 * 4];
            float4 pb = *(const float4*)&p_s[qb2][j4 * 4];
            const float pav[4] = {pa.x, pa.y, pa.z, pa.w};
            const float pbv[4] = {pb.x, pb.y, pb.z, pb.w};
#pragma unroll
            for (int jj = 0; jj < 4; ++jj) {
                float4 vv = *(const float4*)&v_s[j4 * 4 + jj][d0];
                oa[0] += pav[jj] * vv.x; oa[1] += pav[jj] * vv.y;
                oa[2] += pav[jj] * vv.z; oa[3] += pav[jj] * vv.w;
                ob[0] += pbv[jj] * vv.x; ob[1] += pbv[jj] * vv.y;
                ob[2] += pbv[jj] * vv.z; ob[3] += pbv[jj] * vv.w;
            }
        }
        __syncthreads();
    }
    float la = 1.f / l_st[qa], lb = 1.f / l_st[qb2];
    float4 ra = {oa[0] * la, oa[1] * la, oa[2] * la, oa[3] * la};
    float4 rb = {ob[0] * lb, ob[1] * lb, ob[2] * lb, ob[3] * lb};
    *(float4*)&ao[((size_t)b * LQ + q0 + qa) * CDIM + h * 32 + d0] = ra;
    *(float4*)&ao[((size_t)b * LQ + q0 + qb2) * CDIM + h * 32 + d0] = rb;
}

extern "C" void kernel_launch(void* const* d_in, const int* in_sizes, int n_in,
                              void* d_out, int out_size, void* d_ws, size_t ws_size,
                              hipStream_t stream) {
    const float* S_QP = (const float*)d_in[0];
    const float* S_SM = (const float*)d_in[1];
    const float* f_q = (const float*)d_in[2];
    const float* P = (const float*)d_in[3];
    const float* qp_W1 = (const float*)d_in[4];
    const float* qp_b1 = (const float*)d_in[5];
    const float* qp_W2 = (const float*)d_in[6];
    const float* qp_b2 = (const float*)d_in[7];
    const float* phiQ_W1 = (const float*)d_in[8];
    const float* phiQ_b1 = (const float*)d_in[9];
    const float* phiQ_W2 = (const float*)d_in[10];
    const float* phiQ_b2 = (const float*)d_in[11];
    const float* Wq = (const float*)d_in[12];
    const float* bq = (const float*)d_in[13];
    const float* Wk = (const float*)d_in[14];
    const float* bk = (const float*)d_in[15];
    const float* Wv = (const float*)d_in[16];
    const float* bv = (const float*)d_in[17];
    const float* Wo = (const float*)d_in[18];
    const float* bo = (const float*)d_in[19];
    const float* phi_W = (const float*)d_in[20];
    const float* phi_b = (const float*)d_in[21];

    float* out = (float*)d_out;
    float* outS = out;                 // [2,1024,256]
    float* outP = out + 524288;        // [2,2,64,64]
    float* outV = out + 540672;        // [2,1,64,64]

    float* ws = (float*)d_ws;
    float* smean = ws;                 // 512
    float* sb = ws + 512;              // 512
    float* fqT = ws + 1024;            // 2,097,152
    float* Vw = fqT + 2097152;         // 8,192
    float* Qmid = Vw + 8192;           // 524,288
    float* Qb = Qmid + 524288;         // 524,288
    float* qm = Qb + 524288;           // 524,288
    float* km = qm + 524288;           // 2,097,152
    float* vm = km + 2097152;          // 2,097,152
    float* ao = vm + 2097152;          // 524,288
    float* Nm = ao + 524288;           // 524,288   (total ~35.7 MB)

    hipMemsetAsync(smean, 0, 512 * sizeof(float), stream);
    mean_kernel<<<32, 256, 0, stream>>>(S_SM, smean);
    sbias_kernel<<<2, 256, 0, stream>>>(smean, qp_W1, qp_b1, sb);
    transpose_fq<<<dim3(128, 8, 2), 256, 0, stream>>>(f_q, fqT);
    gemm_qp<<<512, 256, 0, stream>>>(fqT, qp_W1 + 65536, sb, qp_W2, qp_b2, P,
                                     outP, outV, Vw);
    gemm256<0><<<512, 256, 0, stream>>>(fqT, nullptr, 256, Wk, bk, nullptr, km);
    gemm256<0><<<512, 256, 0, stream>>>(fqT, nullptr, 256, Wv, bv, nullptr, vm);
    gemm256<1><<<128, 256, 0, stream>>>(S_QP, S_SM, 512, phiQ_W1, phiQ_b1, nullptr, Qmid);
    gemm256<0><<<128, 256, 0, stream>>>(Qmid, nullptr, 256, phiQ_W2, phiQ_b2, nullptr, Qb);
    gemm256<0><<<128, 256, 0, stream>>>(Qb, nullptr, 256, Wq, bq, nullptr, qm);
    attn_kernel<<<256, 256, 0, stream>>>(qm, km, vm, Vw, ao);
    gemm256<0><<<128, 256, 0, stream>>>(ao, nullptr, 256, Wo, bo, nullptr, Nm);
    gemm256<2><<<128, 256, 0, stream>>>(Nm, nullptr, 256, phi_W, phi_b, S_SM, outS);
}

// Round 2
// 356.441 us; speedup vs baseline: 1.8381x; 1.8381x over previous
//
#include <hip/hip_runtime.h>
#include <math.h>

// Shapes (fixed): B=2, Lq=1024, C=256, H=W=64 -> Lk=4096, NC=2, NH=8, D=32.
// Pipeline:
//   1. smean[b,c] = mean_l S_SM                       (mean_kernel, atomics)
//   2. sbias[b,o] = smean @ qp_W1[0:256] + qp_b1      (sbias_kernel)
//   3. fqT[b,l,c] = f_q[b,c,l]                        (transpose_fq)
//   4. h = relu(fqT @ qp_W1[256:512] + sbias) ; P_hat = h @ qp_W2 + qp_b2;
//      V = H(softmax(P_hat)) - H(softmax(P)); Vw2 = V*log2(e)   (gemm_qp)
//   5. k = fqT@Wk+bk (bf16) ; vT = (fqT@Wv+bv)^T head layout (bf16)
//   6. Qmid = relu([S_QP|S_SM]@phiQ_W1+b1); Q = Qmid@phiQ_W2+b2;
//      q = (Q@Wq+bq)*rsq*log2e (bf16)
//   7. MFMA flash attention, kv-split x4 + combine    (attn_mfma, attn_combine)
//   8. N = ao@Wo+bo ; S_IC = S_SM - (N@phi_W+phi_b)   (gemm256)

#define LQ 1024
#define HW 4096
#define CDIM 256
#define LOG2E 1.4426950408889634f

typedef __attribute__((ext_vector_type(8))) short short8;
typedef __attribute__((ext_vector_type(4))) float f32x4;

__device__ __forceinline__ void fma4(float4& a, float s, const float4& w) {
    a.x += s * w.x; a.y += s * w.y; a.z += s * w.z; a.w += s * w.w;
}

__device__ __forceinline__ unsigned short bf16r(float x) {
    unsigned int u = __float_as_uint(x);
    u = (u + 0x7FFFu + ((u >> 16) & 1u)) >> 16;
    return (unsigned short)u;
}

__device__ __forceinline__ float ent2(float a, float b) {
    float m  = fmaxf(a, b);
    float e0 = expf(a - m), e1 = expf(b - m);
    float iz = 1.f / (e0 + e1);
    float p0 = fmaxf(e0 * iz, 1e-8f);
    float p1 = fmaxf(e1 * iz, 1e-8f);
    return -(p0 * logf(p0) + p1 * logf(p1));
}

// ---- 1. mean over Lq
__global__ __launch_bounds__(256) void mean_kernel(const float* __restrict__ S_SM,
                                                   float* __restrict__ smean) {
    int bi = blockIdx.x;
    int b = bi >> 4, l0 = (bi & 15) * 64;
    int c = threadIdx.x;
    const float* p = S_SM + (size_t)b * LQ * CDIM + (size_t)l0 * CDIM + c;
    float acc = 0.f;
#pragma unroll 8
    for (int l = 0; l < 64; ++l) acc += p[(size_t)l * CDIM];
    atomicAdd(&smean[b * CDIM + c], acc * (1.f / 1024.f));
}

// ---- 2. sbias[b,o]
__global__ __launch_bounds__(256) void sbias_kernel(const float* __restrict__ smean,
                                                    const float* __restrict__ qpW1,
                                                    const float* __restrict__ qpb1,
                                                    float* __restrict__ sb) {
    __shared__ float s_s[CDIM];
    int b = blockIdx.x, o = threadIdx.x;
    s_s[o] = smean[b * CDIM + o];
    __syncthreads();
    float acc = qpb1[o];
    for (int c = 0; c < CDIM; ++c) acc += s_s[c] * qpW1[c * CDIM + o];
    sb[b * CDIM + o] = acc;
}

// ---- 3. transpose f_q [B,C,HW] -> fqT [B,HW,C]
__global__ __launch_bounds__(256) void transpose_fq(const float* __restrict__ f_q,
                                                    float* __restrict__ fqT) {
    __shared__ float tile[32][33];
    int b = blockIdx.z;
    int l0 = blockIdx.x * 32, c0 = blockIdx.y * 32;
    int tl = threadIdx.x & 31, tc = threadIdx.x >> 5;
#pragma unroll
    for (int r = 0; r < 4; ++r) {
        int c = c0 + tc + r * 8;
        tile[tc + r * 8][tl] = f_q[(size_t)b * CDIM * HW + (size_t)c * HW + l0 + tl];
    }
    __syncthreads();
    int tc2 = threadIdx.x & 31, tl2 = threadIdx.x >> 5;
#pragma unroll
    for (int r = 0; r < 4; ++r) {
        int l = l0 + tl2 + r * 8;
        fqT[(size_t)b * HW * CDIM + (size_t)l * CDIM + c0 + tc2] = tile[tc2][tl2 + r * 8];
    }
}

// ---- generic GEMM: out[M,256] = epi(A[M,K]@W[K,256] + bias)
// EPI: 0 none, 1 relu, 2 out = src2 - r, 3 r *= scale
// OUT: 0 f32 row-major, 1 bf16 row-major, 2 bf16 transposed head layout [b,h,d,Lk]
template <int EPI, int OUT>
__global__ __launch_bounds__(256) void gemm256(const float* __restrict__ A1,
                                               const float* __restrict__ A2, int K,
                                               const float* __restrict__ W,
                                               const float* __restrict__ bias,
                                               const float* __restrict__ src2,
                                               float scale,
                                               float* __restrict__ out,
                                               unsigned short* __restrict__ out16) {
    __shared__ float a_s[64][20];
    const int t = threadIdx.x;
    const int row0 = blockIdx.x * 16;
    const int p0 = (t >> 6) * 4;
    const int o0 = (t & 63) * 4;
    float4 acc[4];
    acc[0] = acc[1] = acc[2] = acc[3] = float4{0.f, 0.f, 0.f, 0.f};
    for (int k0 = 0; k0 < K; k0 += 64) {
        const float* Asrc = (A2 != nullptr && k0 >= 256) ? A2 : A1;
        int kbase = (A2 != nullptr && k0 >= 256) ? (k0 - 256) : k0;
#pragma unroll
        for (int i = 0; i < 4; ++i) {
            int e = t + i * 256;
            a_s[e & 63][e >> 6] = Asrc[(size_t)(row0 + (e >> 6)) * 256 + kbase + (e & 63)];
        }
        __syncthreads();
#pragma unroll 8
        for (int kk = 0; kk < 64; ++kk) {
            float4 w = *(const float4*)&W[(size_t)(k0 + kk) * 256 + o0];
            float4 a = *(const float4*)&a_s[kk][p0];
            fma4(acc[0], a.x, w);
            fma4(acc[1], a.y, w);
            fma4(acc[2], a.z, w);
            fma4(acc[3], a.w, w);
        }
        __syncthreads();
    }
    float4 bb = *(const float4*)&bias[o0];
    float4 rr[4];
#pragma unroll
    for (int i = 0; i < 4; ++i) {
        float4 r = acc[i];
        r.x += bb.x; r.y += bb.y; r.z += bb.z; r.w += bb.w;
        if (EPI == 1) {
            r.x = fmaxf(r.x, 0.f); r.y = fmaxf(r.y, 0.f);
            r.z = fmaxf(r.z, 0.f); r.w = fmaxf(r.w, 0.f);
        }
        if (EPI == 2) {
            int row = row0 + p0 + i;
            float4 s2 = *(const float4*)&src2[(size_t)row * 256 + o0];
            r.x = s2.x - r.x; r.y = s2.y - r.y; r.z = s2.z - r.z; r.w = s2.w - r.w;
        }
        if (EPI == 3) { r.x *= scale; r.y *= scale; r.z *= scale; r.w *= scale; }
        rr[i] = r;
    }
    if (OUT == 0) {
#pragma unroll
        for (int i = 0; i < 4; ++i)
            *(float4*)&out[(size_t)(row0 + p0 + i) * 256 + o0] = rr[i];
    } else if (OUT == 1) {
#pragma unroll
        for (int i = 0; i < 4; ++i) {
            ushort4 pk = {bf16r(rr[i].x), bf16r(rr[i].y), bf16r(rr[i].z), bf16r(rr[i].w)};
            *(ushort4*)&out16[(size_t)(row0 + p0 + i) * 256 + o0] = pk;
        }
    } else {  // OUT == 2: vT[b][h=c>>5][d=c&31][l]
        const int b = row0 >> 12;
        const int l0r = (row0 & 4095) + p0;
        const float* af = (const float*)rr;
#pragma unroll
        for (int j = 0; j < 4; ++j) {
            int c = o0 + j;
            ushort4 pk = {bf16r(af[j]), bf16r(af[4 + j]), bf16r(af[8 + j]), bf16r(af[12 + j])};
            *(ushort4*)&out16[((size_t)((b * 8 + (c >> 5)) * 32 + (c & 31))) * HW + l0r] = pk;
        }
    }
}

// ---- 4. qp conv GEMM with fused P_hat / entropy / V epilogue.
__global__ __launch_bounds__(256) void gemm_qp(const float* __restrict__ fqT,
                                               const float* __restrict__ W1lo,
                                               const float* __restrict__ sb,
                                               const float* __restrict__ qpW2,
                                               const float* __restrict__ qpb2,
                                               const float* __restrict__ P,
                                               float* __restrict__ outPhat,
                                               float* __restrict__ outV,
                                               float* __restrict__ Vw2) {
    __shared__ float a_s[64][20];
    const int t = threadIdx.x;
    const int row0 = blockIdx.x * 16;
    const int p0 = (t >> 6) * 4;
    const int o0 = (t & 63) * 4;
    float4 acc[4];
    acc[0] = acc[1] = acc[2] = acc[3] = float4{0.f, 0.f, 0.f, 0.f};
    for (int k0 = 0; k0 < 256; k0 += 64) {
#pragma unroll
        for (int i = 0; i < 4; ++i) {
            int e = t + i * 256;
            a_s[e & 63][e >> 6] = fqT[(size_t)(row0 + (e >> 6)) * 256 + k0 + (e & 63)];
        }
        __syncthreads();
#pragma unroll 8
        for (int kk = 0; kk < 64; ++kk) {
            float4 w = *(const float4*)&W1lo[(size_t)(k0 + kk) * 256 + o0];
            float4 a = *(const float4*)&a_s[kk][p0];
            fma4(acc[0], a.x, w);
            fma4(acc[1], a.y, w);
            fma4(acc[2], a.z, w);
            fma4(acc[3], a.w, w);
        }
        __syncthreads();
    }
    const int brow = row0 >> 12;
    float4 bb = *(const float4*)&sb[brow * 256 + o0];
    float w20[4], w21[4];
#pragma unroll
    for (int j = 0; j < 4; ++j) {
        w20[j] = qpW2[(o0 + j) * 2];
        w21[j] = qpW2[(o0 + j) * 2 + 1];
    }
    float c0[4], c1[4];
#pragma unroll
    for (int i = 0; i < 4; ++i) {
        float h0 = fmaxf(((const float*)&acc[i])[0] + bb.x, 0.f);
        float h1 = fmaxf(((const float*)&acc[i])[1] + bb.y, 0.f);
        float h2 = fmaxf(((const float*)&acc[i])[2] + bb.z, 0.f);
        float h3 = fmaxf(((const float*)&acc[i])[3] + bb.w, 0.f);
        c0[i] = h0 * w20[0] + h1 * w20[1] + h2 * w20[2] + h3 * w20[3];
        c1[i] = h0 * w21[0] + h1 * w21[1] + h2 * w21[2] + h3 * w21[3];
    }
#pragma unroll
    for (int m = 1; m < 64; m <<= 1) {
#pragma unroll
        for (int i = 0; i < 4; ++i) {
            c0[i] += __shfl_xor(c0[i], m);
            c1[i] += __shfl_xor(c1[i], m);
        }
    }
    if ((t & 63) == 0) {
        float b20 = qpb2[0], b21 = qpb2[1];
#pragma unroll
        for (int i = 0; i < 4; ++i) {
            int row = row0 + p0 + i;
            int hw = row & 4095, b = row >> 12;
            float ph0 = c0[i] + b20, ph1 = c1[i] + b21;
            float Vv = ent2(ph0, ph1) -
                       ent2(P[(size_t)b * 8192 + hw], P[(size_t)b * 8192 + 4096 + hw]);
            outPhat[(size_t)b * 8192 + hw] = ph0;
            outPhat[(size_t)b * 8192 + 4096 + hw] = ph1;
            outV[b * 4096 + hw] = Vv;
            Vw2[b * 4096 + hw] = Vv * LOG2E;
        }
    }
}

// ---- 7. MFMA flash attention, kv-split x4.
// Block = 4 waves; wave w owns 16 q rows of a 64-q tile. No cross-wave state.
// q pre-scaled by rsq*log2e; bias Vw2 pre-scaled by log2e; softmax in base 2.
__global__ __launch_bounds__(256) void attn_mfma(const unsigned short* __restrict__ qm,
                                                 const unsigned short* __restrict__ km,
                                                 const unsigned short* __restrict__ vt,
                                                 const float* __restrict__ vb2,
                                                 float* __restrict__ Op,
                                                 float* __restrict__ Mp,
                                                 float* __restrict__ Lp) {
    __shared__ __align__(16) unsigned short p_s[4][16][72];  // per-wave P tile, pad 72
    const int blk = blockIdx.x;
    const int sp = blk & 3, qt = (blk >> 2) & 15;
    const int h = (blk >> 6) & 7, b = blk >> 9;
    const int wv = threadIdx.x >> 6, lane = threadIdx.x & 63;
    const int lm = lane & 15, quad = lane >> 4;
    const int q0 = qt * 64 + wv * 16;
    const short8 qf =
        *(const short8*)(qm + ((size_t)(b * LQ + q0 + lm)) * 256 + h * 32 + quad * 8);
    const unsigned short* kb = km + (size_t)b * HW * 256 + h * 32 + quad * 8;
    const unsigned short* vtb = vt + ((size_t)((b * 8 + h) * 32 + lm)) * HW + quad * 8;
    const float* vbb = vb2 + b * HW;
    f32x4 z4 = {0.f, 0.f, 0.f, 0.f};
    f32x4 o0v = z4, o1v = z4;
    float mr[4] = {-INFINITY, -INFINITY, -INFINITY, -INFINITY};
    float lr[4] = {0.f, 0.f, 0.f, 0.f};
    const int kv_lo = sp * 1024, kv_hi = kv_lo + 1024;
    for (int kc = kv_lo; kc < kv_hi; kc += 64) {
        f32x4 st[4];
        float vbf[4];
#pragma unroll
        for (int t = 0; t < 4; ++t) {
            short8 kf = *(const short8*)(kb + (size_t)(kc + t * 16 + lm) * 256);
            st[t] = __builtin_amdgcn_mfma_f32_16x16x32_bf16(qf, kf, z4, 0, 0, 0);
            vbf[t] = vbb[kc + t * 16 + lm];
        }
        float al[4];
#pragma unroll
        for (int r = 0; r < 4; ++r) {
            float z0 = st[0][r] + vbf[0], z1 = st[1][r] + vbf[1];
            float z2 = st[2][r] + vbf[2], z3 = st[3][r] + vbf[3];
            float rm = fmaxf(fmaxf(z0, z1), fmaxf(z2, z3));
            rm = fmaxf(rm, __shfl_xor(rm, 1));
            rm = fmaxf(rm, __shfl_xor(rm, 2));
            rm = fmaxf(rm, __shfl_xor(rm, 4));
            rm = fmaxf(rm, __shfl_xor(rm, 8));
            float mn = fmaxf(mr[r], rm);
            float a = __builtin_amdgcn_exp2f(mr[r] - mn);
            float p0 = __builtin_amdgcn_exp2f(z0 - mn);
            float p1 = __builtin_amdgcn_exp2f(z1 - mn);
            float p2 = __builtin_amdgcn_exp2f(z2 - mn);
            float p3 = __builtin_amdgcn_exp2f(z3 - mn);
            float rs = p0 + p1 + p2 + p3;
            rs += __shfl_xor(rs, 1);
            rs += __shfl_xor(rs, 2);
            rs += __shfl_xor(rs, 4);
            rs += __shfl_xor(rs, 8);
            mr[r] = mn;
            lr[r] = lr[r] * a + rs;
            al[r] = a;
            int row = quad * 4 + r;
            p_s[wv][row][0 * 16 + lm] = bf16r(p0);
            p_s[wv][row][1 * 16 + lm] = bf16r(p1);
            p_s[wv][row][2 * 16 + lm] = bf16r(p2);
            p_s[wv][row][3 * 16 + lm] = bf16r(p3);
        }
        __syncthreads();  // ordering insurance for p_s write->read (wave-private)
#pragma unroll
        for (int r = 0; r < 4; ++r) { o0v[r] *= al[r]; o1v[r] *= al[r]; }
#pragma unroll
        for (int hf = 0; hf < 2; ++hf) {
            short8 pf = *(const short8*)&p_s[wv][lm][hf * 32 + quad * 8];
            short8 vf0 = *(const short8*)(vtb + kc + hf * 32);
            short8 vf1 = *(const short8*)(vtb + (size_t)16 * HW + kc + hf * 32);
            o0v = __builtin_amdgcn_mfma_f32_16x16x32_bf16(pf, vf0, o0v, 0, 0, 0);
            o1v = __builtin_amdgcn_mfma_f32_16x16x32_bf16(pf, vf1, o1v, 0, 0, 0);
        }
    }
    const int rowb = (b * 8 + h) * LQ + q0 + quad * 4;
#pragma unroll
    for (int r = 0; r < 4; ++r) {
        size_t ro = ((size_t)sp * 16384 + rowb + r) * 32;
        Op[ro + lm] = o0v[r];
        Op[ro + 16 + lm] = o1v[r];
        if (lm == 0) {
            Mp[(size_t)sp * 16384 + rowb + r] = mr[r];
            Lp[(size_t)sp * 16384 + rowb + r] = lr[r];
        }
    }
}

// ---- combine 4 kv-splits -> ao [b, q, 256] fp32
__global__ __launch_bounds__(256) void attn_combine(const float* __restrict__ Op,
                                                    const float* __restrict__ Mp,
                                                    const float* __restrict__ Lp,
                                                    float* __restrict__ ao) {
    int gid = blockIdx.x * 256 + threadIdx.x;  // 524288 = 16384 rows * 32 d
    int row = gid >> 5, d = gid & 31;
    float m0 = Mp[row], m1 = Mp[16384 + row], m2 = Mp[2 * 16384 + row],
          m3 = Mp[3 * 16384 + row];
    float mm = fmaxf(fmaxf(m0, m1), fmaxf(m2, m3));
    float w0 = exp2f(m0 - mm), w1 = exp2f(m1 - mm);
    float w2 = exp2f(m2 - mm), w3 = exp2f(m3 - mm);
    float acc = w0 * Op[(size_t)row * 32 + d] +
                w1 * Op[(size_t)(16384 + row) * 32 + d] +
                w2 * Op[(size_t)(2 * 16384 + row) * 32 + d] +
                w3 * Op[(size_t)(3 * 16384 + row) * 32 + d];
    float lsum = w0 * Lp[row] + w1 * Lp[16384 + row] + w2 * Lp[2 * 16384 + row] +
                 w3 * Lp[3 * 16384 + row];
    int b = row >> 13, h = (row >> 10) & 7, q = row & 1023;
    ao[((size_t)(b * LQ + q)) * 256 + h * 32 + d] = acc / lsum;
}

extern "C" void kernel_launch(void* const* d_in, const int* in_sizes, int n_in,
                              void* d_out, int out_size, void* d_ws, size_t ws_size,
                              hipStream_t stream) {
    const float* S_QP = (const float*)d_in[0];
    const float* S_SM = (const float*)d_in[1];
    const float* f_q = (const float*)d_in[2];
    const float* P = (const float*)d_in[3];
    const float* qp_W1 = (const float*)d_in[4];
    const float* qp_b1 = (const float*)d_in[5];
    const float* qp_W2 = (const float*)d_in[6];
    const float* qp_b2 = (const float*)d_in[7];
    const float* phiQ_W1 = (const float*)d_in[8];
    const float* phiQ_b1 = (const float*)d_in[9];
    const float* phiQ_W2 = (const float*)d_in[10];
    const float* phiQ_b2 = (const float*)d_in[11];
    const float* Wq = (const float*)d_in[12];
    const float* bq = (const float*)d_in[13];
    const float* Wk = (const float*)d_in[14];
    const float* bk = (const float*)d_in[15];
    const float* Wv = (const float*)d_in[16];
    const float* bv = (const float*)d_in[17];
    const float* Wo = (const float*)d_in[18];
    const float* bo = (const float*)d_in[19];
    const float* phi_W = (const float*)d_in[20];
    const float* phi_b = (const float*)d_in[21];

    float* out = (float*)d_out;
    float* outS = out;                 // [2,1024,256]
    float* outP = out + 524288;        // [2,2,64,64]
    float* outV = out + 540672;        // [2,1,64,64]

    float* cur = (float*)d_ws;
    float* smean = cur; cur += 512;
    float* sb = cur; cur += 512;
    float* fqT = cur; cur += 2097152;
    float* Vw2 = cur; cur += 8192;
    float* Qmid = cur; cur += 524288;
    float* Qb = cur; cur += 524288;
    unsigned short* qmb = (unsigned short*)cur; cur += 262144;   // 512K bf16
    unsigned short* kmb = (unsigned short*)cur; cur += 1048576;  // 2M bf16
    unsigned short* vtb = (unsigned short*)cur; cur += 1048576;  // 2M bf16 (V^T)
    float* Opart = cur; cur += 2097152;  // [4][16384][32]
    float* Mpart = cur; cur += 65536;
    float* Lpart = cur; cur += 65536;
    float* ao = cur; cur += 524288;
    float* Nm = cur; cur += 524288;     // total ~35.2 MB

    const float qscale = 0.17677669529663687f * LOG2E;  // 1/sqrt(32) * log2(e)

    hipMemsetAsync(smean, 0, 512 * sizeof(float), stream);
    mean_kernel<<<32, 256, 0, stream>>>(S_SM, smean);
    sbias_kernel<<<2, 256, 0, stream>>>(smean, qp_W1, qp_b1, sb);
    transpose_fq<<<dim3(128, 8, 2), 256, 0, stream>>>(f_q, fqT);
    gemm_qp<<<512, 256, 0, stream>>>(fqT, qp_W1 + 65536, sb, qp_W2, qp_b2, P,
                                     outP, outV, Vw2);
    gemm256<0, 1><<<512, 256, 0, stream>>>(fqT, nullptr, 256, Wk, bk, nullptr, 0.f,
                                           nullptr, kmb);
    gemm256<0, 2><<<512, 256, 0, stream>>>(fqT, nullptr, 256, Wv, bv, nullptr, 0.f,
                                           nullptr, vtb);
    gemm256<1, 0><<<128, 256, 0, stream>>>(S_QP, S_SM, 512, phiQ_W1, phiQ_b1, nullptr,
                                           0.f, Qmid, nullptr);
    gemm256<0, 0><<<128, 256, 0, stream>>>(Qmid, nullptr, 256, phiQ_W2, phiQ_b2,
                                           nullptr, 0.f, Qb, nullptr);
    gemm256<3, 1><<<128, 256, 0, stream>>>(Qb, nullptr, 256, Wq, bq, nullptr, qscale,
                                           nullptr, qmb);
    attn_mfma<<<1024, 256, 0, stream>>>(qmb, kmb, vtb, Vw2, Opart, Mpart, Lpart);
    attn_combine<<<2048, 256, 0, stream>>>(Opart, Mpart, Lpart, ao);
    gemm256<0, 0><<<128, 256, 0, stream>>>(ao, nullptr, 256, Wo, bo, nullptr, 0.f,
                                           Nm, nullptr);
    gemm256<2, 0><<<128, 256, 0, stream>>>(Nm, nullptr, 256, phi_W, phi_b, S_SM, 0.f,
                                           outS, nullptr);
}

// Round 3
// 256.396 us; speedup vs baseline: 2.5553x; 1.3902x over previous
//
#include <hip/hip_runtime.h>
#include <math.h>

// Shapes (fixed): B=2, Lq=1024, C=256, H=W=64 -> Lk=4096, NC=2, NH=8, D=32.
// All heavy GEMMs are bf16 MFMA (16x16x32). Weights pre-transposed to
// Wt[n][k] bf16 by prep_weights. Flash attention: kv-split x8, base-2
// softmax, row-sum via MFMA-with-ones, permuted kv order so the P LDS
// round-trip is ushort4 writes.

#define LQ 1024
#define HW 4096
#define LOG2E 1.4426950408889634f

typedef __attribute__((ext_vector_type(8))) short short8;
typedef __attribute__((ext_vector_type(4))) float f32x4;
typedef unsigned short u16;

__device__ __forceinline__ u16 bf16r(float x) {
    unsigned int u = __float_as_uint(x);
    u = (u + 0x7FFFu + ((u >> 16) & 1u)) >> 16;
    return (u16)u;
}

__device__ __forceinline__ float ent2(float a, float b) {
    float m  = fmaxf(a, b);
    float e0 = expf(a - m), e1 = expf(b - m);
    float iz = 1.f / (e0 + e1);
    float p0 = fmaxf(e0 * iz, 1e-8f);
    float p1 = fmaxf(e1 * iz, 1e-8f);
    return -(p0 * logf(p0) + p1 * logf(p1));
}

// ---- mean over Lq
__global__ __launch_bounds__(256) void mean_kernel(const float* __restrict__ S_SM,
                                                   float* __restrict__ smean) {
    int bi = blockIdx.x;
    int b = bi >> 4, l0 = (bi & 15) * 64;
    int c = threadIdx.x;
    const float* p = S_SM + (size_t)b * LQ * 256 + (size_t)l0 * 256 + c;
    float acc = 0.f;
#pragma unroll 8
    for (int l = 0; l < 64; ++l) acc += p[(size_t)l * 256];
    atomicAdd(&smean[b * 256 + c], acc * (1.f / 1024.f));
}

// ---- sbias[b,o] = smean @ qp_W1[0:256] + qp_b1  (fp32, tiny)
__global__ __launch_bounds__(256) void sbias_kernel(const float* __restrict__ smean,
                                                    const float* __restrict__ qpW1,
                                                    const float* __restrict__ qpb1,
                                                    float* __restrict__ sb) {
    __shared__ float s_s[256];
    int b = blockIdx.x, o = threadIdx.x;
    s_s[o] = smean[b * 256 + o];
    __syncthreads();
    float acc = qpb1[o];
    for (int c = 0; c < 256; ++c) acc += s_s[c] * qpW1[c * 256 + o];
    sb[b * 256 + o] = acc;
}

// ---- one-shot: transpose+convert all weights W[K,256] f32 -> Wt[256,K] bf16
__global__ __launch_bounds__(256) void prep_weights(
    const float* s0, const float* s1, const float* s2, const float* s3,
    const float* s4, const float* s5, const float* s6, const float* s7,
    u16* d0, u16* d1, u16* d2, u16* d3, u16* d4, u16* d5, u16* d6, u16* d7) {
    __shared__ float tile[32][33];
    int bid = blockIdx.x;
    const float* S; u16* D; int K;
    if (bid < 64)       { S = s0; D = d0; K = 256; }
    else if (bid < 128) { S = s1; D = d1; K = 256; bid -= 64; }
    else if (bid < 192) { S = s2; D = d2; K = 256; bid -= 128; }
    else if (bid < 320) { S = s3; D = d3; K = 512; bid -= 192; }
    else if (bid < 384) { S = s4; D = d4; K = 256; bid -= 320; }
    else if (bid < 448) { S = s5; D = d5; K = 256; bid -= 384; }
    else if (bid < 512) { S = s6; D = d6; K = 256; bid -= 448; }
    else                { S = s7; D = d7; K = 256; bid -= 512; }
    int KT = K >> 5;
    int tk = bid % KT, tn = bid / KT;
    int cc = threadIdx.x & 31, rb = threadIdx.x >> 5;
#pragma unroll
    for (int i = 0; i < 4; ++i) {
        int rr = rb + i * 8;
        tile[rr][cc] = S[(size_t)(tk * 32 + rr) * 256 + tn * 32 + cc];
    }
    __syncthreads();
#pragma unroll
    for (int i = 0; i < 4; ++i) {
        int rr = rb + i * 8;  // n within tile
        D[(size_t)(tn * 32 + rr) * K + tk * 32 + cc] = bf16r(tile[cc][rr]);
    }
}

// ---- Scat[row][0:256]=bf16(S_QP), [256:512]=bf16(S_SM)
__global__ __launch_bounds__(256) void convert_S(const float* __restrict__ S_QP,
                                                 const float* __restrict__ S_SM,
                                                 u16* __restrict__ Scat) {
    int idx = (blockIdx.x * 256 + threadIdx.x) * 2;
    int row = idx >> 9, col = idx & 511;
    const float* src = (col < 256) ? &S_QP[(size_t)row * 256 + col]
                                   : &S_SM[(size_t)row * 256 + col - 256];
    float2 v = *(const float2*)src;
    ushort2 pk = {bf16r(v.x), bf16r(v.y)};
    *(ushort2*)&Scat[idx] = pk;
}

// ---- transpose f_q [B,C,HW] -> fqT [B,HW,C] bf16
__global__ __launch_bounds__(256) void transpose_fq(const float* __restrict__ f_q,
                                                    u16* __restrict__ fqT) {
    __shared__ float tile[32][33];
    int b = blockIdx.z;
    int l0 = blockIdx.x * 32, c0 = blockIdx.y * 32;
    int tl = threadIdx.x & 31, tc = threadIdx.x >> 5;
#pragma unroll
    for (int r = 0; r < 4; ++r) {
        int c = c0 + tc + r * 8;
        tile[tc + r * 8][tl] = f_q[(size_t)b * 256 * HW + (size_t)c * HW + l0 + tl];
    }
    __syncthreads();
    int tc2 = threadIdx.x & 31, tl2 = threadIdx.x >> 5;
#pragma unroll
    for (int r = 0; r < 4; ++r) {
        int l = l0 + tl2 + r * 8;
        fqT[(size_t)b * HW * 256 + (size_t)l * 256 + c0 + tc2] = bf16r(tile[tc2][tl2 + r * 8]);
    }
}

// ---- MFMA GEMM: out[M,256] = epi(A[M,KDIM] @ Wt^T + bias)
// Wt[n][k] bf16. Block = 4 waves; wave = 16*RS rows x 32 cols.
// grid = (M / (16*RS)) * 2. EPI: 0 none,1 relu,2 src2-r,3 *scale.
// OUT: 0 f32, 1 bf16 row-major, 2 bf16 vT head layout, kv-permuted.
template <int KDIM, int EPI, int OUT>
__global__ __launch_bounds__(256) void mgemm(const u16* __restrict__ A,
                                             const u16* __restrict__ Wt,
                                             const float* __restrict__ bias,
                                             const float* __restrict__ src2,
                                             float scale, float* __restrict__ out,
                                             u16* __restrict__ out16) {
    constexpr int NK = KDIM / 32;
    constexpr int RS = (KDIM == 256) ? 2 : 1;
    const int wv = threadIdx.x >> 6, lane = threadIdx.x & 63;
    const int lm = lane & 15, quad = lane >> 4;
    const int row0 = (blockIdx.x >> 1) * (16 * RS);
    const int c0 = (blockIdx.x & 1) * 128 + wv * 32;
    short8 af[RS][NK];
#pragma unroll
    for (int s = 0; s < RS; ++s)
#pragma unroll
        for (int i = 0; i < NK; ++i)
            af[s][i] = *(const short8*)(A + (size_t)(row0 + s * 16 + lm) * KDIM +
                                        i * 32 + quad * 8);
    f32x4 acc[RS][2];
#pragma unroll
    for (int j = 0; j < 2; ++j) {
        float bv = bias[c0 + j * 16 + lm];
#pragma unroll
        for (int s = 0; s < RS; ++s) acc[s][j] = f32x4{bv, bv, bv, bv};
    }
#pragma unroll
    for (int j = 0; j < 2; ++j) {
        const u16* wp = Wt + (size_t)(c0 + j * 16 + lm) * KDIM + quad * 8;
#pragma unroll
        for (int i = 0; i < NK; ++i) {
            short8 bf = *(const short8*)(wp + i * 32);
#pragma unroll
            for (int s = 0; s < RS; ++s)
                acc[s][j] = __builtin_amdgcn_mfma_f32_16x16x32_bf16(af[s][i], bf,
                                                                    acc[s][j], 0, 0, 0);
        }
    }
#pragma unroll
    for (int s = 0; s < RS; ++s)
#pragma unroll
        for (int j = 0; j < 2; ++j) {
            int n = c0 + j * 16 + lm;
#pragma unroll
            for (int r = 0; r < 4; ++r) {
                int row = row0 + s * 16 + quad * 4 + r;
                float v = acc[s][j][r];
                if (EPI == 1) v = fmaxf(v, 0.f);
                if (EPI == 3) v *= scale;
                if (EPI == 2) v = src2[(size_t)row * 256 + n] - v;
                if (OUT == 0) {
                    out[(size_t)row * 256 + n] = v;
                } else if (OUT == 1) {
                    out16[(size_t)row * 256 + n] = bf16r(v);
                } else {
                    int b = row >> 12, l = row & 4095;
                    int pos = (l & ~63) + ((l & 15) << 2) + ((l >> 4) & 3);
                    out16[((size_t)((b * 8 + (n >> 5)) * 32 + (n & 31))) * HW + pos] =
                        bf16r(v);
                }
            }
        }
}

// ---- qp conv GEMM (MFMA) with fused P_hat / entropy / V epilogue.
// Block = 16 rows x 256 cols (4 col-waves of 64). grid = 8192/16 = 512.
__global__ __launch_bounds__(256) void gemm_qp_mfma(
    const u16* __restrict__ A, const u16* __restrict__ Wt,
    const float* __restrict__ sb, const float* __restrict__ qpW2,
    const float* __restrict__ qpb2, const float* __restrict__ P,
    float* __restrict__ outPhat, float* __restrict__ outV,
    float* __restrict__ Vw2) {
    __shared__ float red[4][16][2];
    const int wv = threadIdx.x >> 6, lane = threadIdx.x & 63;
    const int lm = lane & 15, quad = lane >> 4;
    const int row0 = blockIdx.x * 16;
    const int b = row0 >> 12;
    short8 af[8];
#pragma unroll
    for (int i = 0; i < 8; ++i)
        af[i] = *(const short8*)(A + (size_t)(row0 + lm) * 256 + i * 32 + quad * 8);
    float c0p[4] = {0.f, 0.f, 0.f, 0.f}, c1p[4] = {0.f, 0.f, 0.f, 0.f};
#pragma unroll
    for (int j = 0; j < 4; ++j) {
        int n = wv * 64 + j * 16 + lm;
        float bv = sb[b * 256 + n];
        f32x4 acc = {bv, bv, bv, bv};
        const u16* wp = Wt + (size_t)n * 256 + quad * 8;
#pragma unroll
        for (int i = 0; i < 8; ++i) {
            short8 bf = *(const short8*)(wp + i * 32);
            acc = __builtin_amdgcn_mfma_f32_16x16x32_bf16(af[i], bf, acc, 0, 0, 0);
        }
        float w20 = qpW2[n * 2], w21 = qpW2[n * 2 + 1];
#pragma unroll
        for (int r = 0; r < 4; ++r) {
            float hh = fmaxf(acc[r], 0.f);
            c0p[r] += hh * w20;
            c1p[r] += hh * w21;
        }
    }
#pragma unroll
    for (int m = 1; m < 16; m <<= 1) {
#pragma unroll
        for (int r = 0; r < 4; ++r) {
            c0p[r] += __shfl_xor(c0p[r], m);
            c1p[r] += __shfl_xor(c1p[r], m);
        }
    }
    if (lm == 0) {
#pragma unroll
        for (int r = 0; r < 4; ++r) {
            red[wv][quad * 4 + r][0] = c0p[r];
            red[wv][quad * 4 + r][1] = c1p[r];
        }
    }
    __syncthreads();
    int t = threadIdx.x;
    if (t < 16) {
        float ph0 = red[0][t][0] + red[1][t][0] + red[2][t][0] + red[3][t][0] + qpb2[0];
        float ph1 = red[0][t][1] + red[1][t][1] + red[2][t][1] + red[3][t][1] + qpb2[1];
        int grow = row0 + t;
        int hw = grow & 4095;
        float Vv = ent2(ph0, ph1) -
                   ent2(P[(size_t)b * 8192 + hw], P[(size_t)b * 8192 + 4096 + hw]);
        outPhat[(size_t)b * 8192 + hw] = ph0;
        outPhat[(size_t)b * 8192 + 4096 + hw] = ph1;
        outV[b * 4096 + hw] = Vv;
        Vw2[b * 4096 + hw] = Vv * LOG2E;
    }
}

// ---- MFMA flash attention, kv-split x8, base-2 softmax.
// Wave-private P tile: stored in kv-permuted order u = lm*4 + t (ushort4
// writes); V was written by mgemm<.,.,2> in matching permuted order.
// Row-sum of P via MFMA with ones B-fragment (consistent with bf16 P).
__global__ __launch_bounds__(256) void attn_mfma(const u16* __restrict__ qm,
                                                 const u16* __restrict__ km,
                                                 const u16* __restrict__ vt,
                                                 const float* __restrict__ vb2,
                                                 u16* __restrict__ Op,
                                                 float* __restrict__ Mp,
                                                 float* __restrict__ Lp) {
    __shared__ __align__(16) u16 p_s[4][16][80];  // stride 160B (16B mult)
    const int blk = blockIdx.x;
    const int sp = blk & 7, qt = (blk >> 3) & 15, h = (blk >> 7) & 7, b = blk >> 10;
    const int wv = threadIdx.x >> 6, lane = threadIdx.x & 63;
    const int lm = lane & 15, quad = lane >> 4;
    const int q0 = qt * 64 + wv * 16;
    const short8 qf =
        *(const short8*)(qm + ((size_t)(b * LQ + q0 + lm)) * 256 + h * 32 + quad * 8);
    const u16* kb = km + (size_t)b * HW * 256 + h * 32 + quad * 8;
    const u16* vtb = vt + ((size_t)((b * 8 + h) * 32 + lm)) * HW + quad * 8;
    const float* vbb = vb2 + b * HW;
    const short os = (short)0x3F80;  // bf16 1.0
    const short8 ones = {os, os, os, os, os, os, os, os};
    const f32x4 z4 = {0.f, 0.f, 0.f, 0.f};
    f32x4 o0v = z4, o1v = z4;
    float mr[4] = {-INFINITY, -INFINITY, -INFINITY, -INFINITY};
    float lr[4] = {0.f, 0.f, 0.f, 0.f};
    const int kv_lo = sp * 512;
    for (int kc = kv_lo; kc < kv_lo + 512; kc += 64) {
        f32x4 st[4];
        float vbf[4];
#pragma unroll
        for (int t = 0; t < 4; ++t) {
            short8 kf = *(const short8*)(kb + (size_t)(kc + t * 16 + lm) * 256);
            st[t] = __builtin_amdgcn_mfma_f32_16x16x32_bf16(qf, kf, z4, 0, 0, 0);
            vbf[t] = vbb[kc + t * 16 + lm];
        }
        float al[4];
#pragma unroll
        for (int r = 0; r < 4; ++r) {
            float z0 = st[0][r] + vbf[0], z1 = st[1][r] + vbf[1];
            float z2 = st[2][r] + vbf[2], z3 = st[3][r] + vbf[3];
            float rm = fmaxf(fmaxf(z0, z1), fmaxf(z2, z3));
            rm = fmaxf(rm, __shfl_xor(rm, 1));
            rm = fmaxf(rm, __shfl_xor(rm, 2));
            rm = fmaxf(rm, __shfl_xor(rm, 4));
            rm = fmaxf(rm, __shfl_xor(rm, 8));
            float mn = fmaxf(mr[r], rm);
            al[r] = __builtin_amdgcn_exp2f(mr[r] - mn);
            mr[r] = mn;
            float p0 = __builtin_amdgcn_exp2f(z0 - mn);
            float p1 = __builtin_amdgcn_exp2f(z1 - mn);
            float p2 = __builtin_amdgcn_exp2f(z2 - mn);
            float p3 = __builtin_amdgcn_exp2f(z3 - mn);
            ushort4 pk = {(u16)(__float_as_uint(p0) >> 16),
                          (u16)(__float_as_uint(p1) >> 16),
                          (u16)(__float_as_uint(p2) >> 16),
                          (u16)(__float_as_uint(p3) >> 16)};
            *(ushort4*)&p_s[wv][quad * 4 + r][lm * 4] = pk;  // u = lm*4 + t
        }
#pragma unroll
        for (int r = 0; r < 4; ++r) { o0v[r] *= al[r]; o1v[r] *= al[r]; }
        f32x4 rsv = z4;
        // p_s is wave-private; DS pipe is in-order within a wave -> no barrier.
#pragma unroll
        for (int hf = 0; hf < 2; ++hf) {
            short8 pf = *(const short8*)&p_s[wv][lm][hf * 32 + quad * 8];
            rsv = __builtin_amdgcn_mfma_f32_16x16x32_bf16(pf, ones, rsv, 0, 0, 0);
            short8 vf0 = *(const short8*)(vtb + kc + hf * 32);
            short8 vf1 = *(const short8*)(vtb + (size_t)16 * HW + kc + hf * 32);
            o0v = __builtin_amdgcn_mfma_f32_16x16x32_bf16(pf, vf0, o0v, 0, 0, 0);
            o1v = __builtin_amdgcn_mfma_f32_16x16x32_bf16(pf, vf1, o1v, 0, 0, 0);
        }
#pragma unroll
        for (int r = 0; r < 4; ++r) lr[r] = lr[r] * al[r] + rsv[r];
    }
    const int rowb = (b * 8 + h) * LQ + q0 + quad * 4;
#pragma unroll
    for (int r = 0; r < 4; ++r) {
        size_t ro = ((size_t)sp * 16384 + rowb + r) * 32;
        Op[ro + lm] = bf16r(o0v[r]);
        Op[ro + 16 + lm] = bf16r(o1v[r]);
        if (lm == 0) {
            Mp[(size_t)sp * 16384 + rowb + r] = mr[r];
            Lp[(size_t)sp * 16384 + rowb + r] = lr[r];
        }
    }
}

// ---- combine 8 kv-splits -> aob [b,q,256] bf16
__global__ __launch_bounds__(256) void attn_combine(const u16* __restrict__ Op,
                                                    const float* __restrict__ Mp,
                                                    const float* __restrict__ Lp,
                                                    u16* __restrict__ aob) {
    int gid = blockIdx.x * 256 + threadIdx.x;  // 524288
    int row = gid >> 5, d = gid & 31;
    float m[8];
    float mm = -INFINITY;
#pragma unroll
    for (int s = 0; s < 8; ++s) {
        m[s] = Mp[s * 16384 + row];
        mm = fmaxf(mm, m[s]);
    }
    float acc = 0.f, ls = 0.f;
#pragma unroll
    for (int s = 0; s < 8; ++s) {
        float w = __builtin_amdgcn_exp2f(m[s] - mm);
        float ov = __uint_as_float((unsigned)Op[((size_t)s * 16384 + row) * 32 + d] << 16);
        acc += w * ov;
        ls += w * Lp[s * 16384 + row];
    }
    int b = row >> 13, h = (row >> 10) & 7, q = row & 1023;
    aob[((size_t)(b * LQ + q)) * 256 + h * 32 + d] = bf16r(acc / ls);
}

extern "C" void kernel_launch(void* const* d_in, const int* in_sizes, int n_in,
                              void* d_out, int out_size, void* d_ws, size_t ws_size,
                              hipStream_t stream) {
    const float* S_QP = (const float*)d_in[0];
    const float* S_SM = (const float*)d_in[1];
    const float* f_q = (const float*)d_in[2];
    const float* P = (const float*)d_in[3];
    const float* qp_W1 = (const float*)d_in[4];
    const float* qp_b1 = (const float*)d_in[5];
    const float* qp_W2 = (const float*)d_in[6];
    const float* qp_b2 = (const float*)d_in[7];
    const float* phiQ_W1 = (const float*)d_in[8];
    const float* phiQ_b1 = (const float*)d_in[9];
    const float* phiQ_W2 = (const float*)d_in[10];
    const float* phiQ_b2 = (const float*)d_in[11];
    const float* Wq = (const float*)d_in[12];
    const float* bq = (const float*)d_in[13];
    const float* Wk = (const float*)d_in[14];
    const float* bk = (const float*)d_in[15];
    const float* Wv = (const float*)d_in[16];
    const float* bv = (const float*)d_in[17];
    const float* Wo = (const float*)d_in[18];
    const float* bo = (const float*)d_in[19];
    const float* phi_W = (const float*)d_in[20];
    const float* phi_b = (const float*)d_in[21];

    float* out = (float*)d_out;
    float* outS = out;            // [2,1024,256]
    float* outP = out + 524288;   // [2,2,64,64]
    float* outV = out + 540672;   // [2,1,64,64]

    // workspace (~30.6 MB)
    float* smean = (float*)d_ws;            // 512
    float* sb = smean + 512;                // 512
    float* Vw2 = sb + 512;                  // 8192
    float* Mp = Vw2 + 8192;                 // 131072
    float* Lp = Mp + 131072;                // 131072
    u16* qpW1loT = (u16*)(Lp + 131072);     // 65536
    u16* WkT = qpW1loT + 65536;             // 65536
    u16* WvT = WkT + 65536;                 // 65536
    u16* phiQ1T = WvT + 65536;              // 131072
    u16* phiQ2T = phiQ1T + 131072;          // 65536
    u16* WqT = phiQ2T + 65536;              // 65536
    u16* WoT = WqT + 65536;                 // 65536
    u16* phiWT = WoT + 65536;               // 65536
    u16* fqT16 = phiWT + 65536;             // 2097152
    u16* Scat = fqT16 + 2097152;            // 1048576
    u16* Qmid = Scat + 1048576;             // 524288
    u16* Qb = Qmid + 524288;                // 524288
    u16* qmb = Qb + 524288;                 // 524288
    u16* kmb = qmb + 524288;                // 2097152
    u16* vtb = kmb + 2097152;               // 2097152 (V^T, kv-permuted)
    u16* Op16 = vtb + 2097152;              // 4194304
    u16* aob = Op16 + 4194304;              // 524288
    u16* Nm = aob + 524288;                 // 524288

    const float qscale = 0.17677669529663687f * LOG2E;  // 1/sqrt(32)*log2e

    hipMemsetAsync(smean, 0, 512 * sizeof(float), stream);
    mean_kernel<<<32, 256, 0, stream>>>(S_SM, smean);
    sbias_kernel<<<2, 256, 0, stream>>>(smean, qp_W1, qp_b1, sb);
    prep_weights<<<576, 256, 0, stream>>>(qp_W1 + 65536, Wk, Wv, phiQ_W1, phiQ_W2,
                                          Wq, Wo, phi_W, qpW1loT, WkT, WvT, phiQ1T,
                                          phiQ2T, WqT, WoT, phiWT);
    convert_S<<<2048, 256, 0, stream>>>(S_QP, S_SM, Scat);
    transpose_fq<<<dim3(128, 8, 2), 256, 0, stream>>>(f_q, fqT16);
    gemm_qp_mfma<<<512, 256, 0, stream>>>(fqT16, qpW1loT, sb, qp_W2, qp_b2, P,
                                          outP, outV, Vw2);
    mgemm<256, 0, 1><<<512, 256, 0, stream>>>(fqT16, WkT, bk, nullptr, 0.f,
                                              nullptr, kmb);
    mgemm<256, 0, 2><<<512, 256, 0, stream>>>(fqT16, WvT, bv, nullptr, 0.f,
                                              nullptr, vtb);
    mgemm<512, 1, 1><<<256, 256, 0, stream>>>(Scat, phiQ1T, phiQ_b1, nullptr, 0.f,
                                              nullptr, Qmid);
    mgemm<256, 0, 1><<<128, 256, 0, stream>>>(Qmid, phiQ2T, phiQ_b2, nullptr, 0.f,
                                              nullptr, Qb);
    mgemm<256, 3, 1><<<128, 256, 0, stream>>>(Qb, WqT, bq, nullptr, qscale,
                                              nullptr, qmb);
    attn_mfma<<<2048, 256, 0, stream>>>(qmb, kmb, vtb, Vw2, Op16, Mp, Lp);
    attn_combine<<<2048, 256, 0, stream>>>(Op16, Mp, Lp, aob);
    mgemm<256, 0, 1><<<128, 256, 0, stream>>>(aob, WoT, bo, nullptr, 0.f,
                                              nullptr, Nm);
    mgemm<256, 2, 0><<<128, 256, 0, stream>>>(Nm, phiWT, phi_b, S_SM, 0.f,
                                              outS, nullptr);
}

// Round 4
// 227.768 us; speedup vs baseline: 2.8765x; 1.1257x over previous
//
#include <hip/hip_runtime.h>
#include <math.h>

// B=2, Lq=1024, C=256, H=W=64 -> Lk=4096, NC=2, NH=8, D=32.
// R4: attention stages K/V in LDS via global_load_lds (x4 traffic cut),
// triple-buffered prefetch w/ 1 barrier/chunk, blk%8==h XCD swizzle.
// GEMMs: gemm_fq fuses qp-conv+K+V (A loaded once); phiQ_W2@Wq and
// Wo@phi_W folded into single fused weights (tiny MFMA GEMMs at prep).

#define LQ 1024
#define HW 4096
#define LOG2E 1.4426950408889634f

typedef __attribute__((ext_vector_type(8))) short short8;
typedef __attribute__((ext_vector_type(4))) float f32x4;
typedef unsigned short u16;

__device__ __forceinline__ u16 bf16r(float x) {
    unsigned int u = __float_as_uint(x);
    u = (u + 0x7FFFu + ((u >> 16) & 1u)) >> 16;
    return (u16)u;
}

__device__ __forceinline__ float ent2(float a, float b) {
    float m  = fmaxf(a, b);
    float e0 = expf(a - m), e1 = expf(b - m);
    float iz = 1.f / (e0 + e1);
    float p0 = fmaxf(e0 * iz, 1e-8f);
    float p1 = fmaxf(e1 * iz, 1e-8f);
    return -(p0 * logf(p0) + p1 * logf(p1));
}

typedef __attribute__((address_space(1))) const unsigned int gas_u32;
typedef __attribute__((address_space(3))) unsigned int las_u32;
__device__ __forceinline__ void glds16(const void* g, void* l) {
    __builtin_amdgcn_global_load_lds((gas_u32*)g, (las_u32*)l, 16, 0, 0);
}

// ---- mean over Lq
__global__ __launch_bounds__(256) void mean_kernel(const float* __restrict__ S_SM,
                                                   float* __restrict__ smean) {
    int bi = blockIdx.x;
    int b = bi >> 4, l0 = (bi & 15) * 64;
    int c = threadIdx.x;
    const float* p = S_SM + (size_t)b * LQ * 256 + (size_t)l0 * 256 + c;
    float acc = 0.f;
#pragma unroll 8
    for (int l = 0; l < 64; ++l) acc += p[(size_t)l * 256];
    atomicAdd(&smean[b * 256 + c], acc * (1.f / 1024.f));
}

// ---- sbias[b,o] = smean @ qp_W1[0:256] + qp_b1
__global__ __launch_bounds__(256) void sbias_kernel(const float* __restrict__ smean,
                                                    const float* __restrict__ qpW1,
                                                    const float* __restrict__ qpb1,
                                                    float* __restrict__ sb) {
    __shared__ float s_s[256];
    int b = blockIdx.x, o = threadIdx.x;
    s_s[o] = smean[b * 256 + o];
    __syncthreads();
    float acc = qpb1[o];
    for (int c = 0; c < 256; ++c) acc += s_s[c] * qpW1[c * 256 + o];
    sb[b * 256 + o] = acc;
}

// ---- weights: transpose W[K,256]->Wt[256,K] bf16 (6 mats) + straight
// bf16 converts of phiQ_W2, Wo (for the weight-fusion GEMMs).
__global__ __launch_bounds__(256) void prep_weights(
    const float* s0, const float* s1, const float* s2, const float* s3,
    const float* s4, const float* s5, const float* s6, const float* s7,
    u16* d0, u16* d1, u16* d2, u16* d3, u16* d4, u16* d5, u16* d6, u16* d7) {
    __shared__ float tile[32][33];
    int bid = blockIdx.x;
    if (bid >= 448) {  // straight converts
        int b2 = bid - 448;
        const float* S = (b2 < 64) ? s6 : s7;
        u16* D = (b2 < 64) ? d6 : d7;
        int idx = ((b2 & 63) * 256 + threadIdx.x) * 4;
        float4 v = *(const float4*)&S[idx];
        ushort4 pk = {bf16r(v.x), bf16r(v.y), bf16r(v.z), bf16r(v.w)};
        *(ushort4*)&D[idx] = pk;
        return;
    }
    const float* S; u16* D; int K;
    if (bid < 64)       { S = s0; D = d0; K = 256; }
    else if (bid < 128) { S = s1; D = d1; K = 256; bid -= 64; }
    else if (bid < 192) { S = s2; D = d2; K = 256; bid -= 128; }
    else if (bid < 320) { S = s3; D = d3; K = 512; bid -= 192; }
    else if (bid < 384) { S = s4; D = d4; K = 256; bid -= 320; }
    else                { S = s5; D = d5; K = 256; bid -= 384; }
    int KT = K >> 5;
    int tk = bid % KT, tn = bid / KT;
    int cc = threadIdx.x & 31, rb = threadIdx.x >> 5;
#pragma unroll
    for (int i = 0; i < 4; ++i) {
        int rr = rb + i * 8;
        tile[rr][cc] = S[(size_t)(tk * 32 + rr) * 256 + tn * 32 + cc];
    }
    __syncthreads();
#pragma unroll
    for (int i = 0; i < 4; ++i) {
        int rr = rb + i * 8;
        D[(size_t)(tn * 32 + rr) * K + tk * 32 + cc] = bf16r(tile[cc][rr]);
    }
}

// ---- fused biases: bf1 = phiQ_b2@Wq + bq ; bf2 = bo@phi_W + phi_b
__global__ __launch_bounds__(256) void bias_fuse(const float* pb2, const float* Wq,
                                                 const float* bq, const float* bo,
                                                 const float* phiW, const float* phib,
                                                 float* bf1, float* bf2) {
    int n = threadIdx.x;
    if (blockIdx.x == 0) {
        float a = bq[n];
        for (int c = 0; c < 256; ++c) a += pb2[c] * Wq[c * 256 + n];
        bf1[n] = a;
    } else {
        float a = phib[n];
        for (int c = 0; c < 256; ++c) a += bo[c] * phiW[c * 256 + n];
        bf2[n] = a;
    }
}

// ---- transpose f_q [B,C,HW] -> fqT [B,HW,C] bf16
__global__ __launch_bounds__(256) void transpose_fq(const float* __restrict__ f_q,
                                                    u16* __restrict__ fqT) {
    __shared__ float tile[32][33];
    int b = blockIdx.z;
    int l0 = blockIdx.x * 32, c0 = blockIdx.y * 32;
    int tl = threadIdx.x & 31, tc = threadIdx.x >> 5;
#pragma unroll
    for (int r = 0; r < 4; ++r) {
        int c = c0 + tc + r * 8;
        tile[tc + r * 8][tl] = f_q[(size_t)b * 256 * HW + (size_t)c * HW + l0 + tl];
    }
    __syncthreads();
    int tc2 = threadIdx.x & 31, tl2 = threadIdx.x >> 5;
#pragma unroll
    for (int r = 0; r < 4; ++r) {
        int l = l0 + tl2 + r * 8;
        fqT[(size_t)b * HW * 256 + (size_t)l * 256 + c0 + tc2] = bf16r(tile[tc2][tl2 + r * 8]);
    }
}

// ---- MFMA GEMM: out[M,256] = epi(A[M,256] @ Wt^T + bias), A bf16.
// EPI: 0 none,2 src2-r,3 *scale. OUT: 0 f32, 1 bf16.
template <int EPI, int OUT>
__global__ __launch_bounds__(256) void mgemm(const u16* __restrict__ A,
                                             const u16* __restrict__ Wt,
                                             const float* __restrict__ bias,
                                             const float* __restrict__ src2,
                                             float scale, float* __restrict__ out,
                                             u16* __restrict__ out16) {
    const int wv = threadIdx.x >> 6, lane = threadIdx.x & 63;
    const int lm = lane & 15, quad = lane >> 4;
    const int row0 = (blockIdx.x >> 1) * 32;
    const int c0 = (blockIdx.x & 1) * 128 + wv * 32;
    short8 af[2][8];
#pragma unroll
    for (int s = 0; s < 2; ++s)
#pragma unroll
        for (int i = 0; i < 8; ++i)
            af[s][i] = *(const short8*)(A + (size_t)(row0 + s * 16 + lm) * 256 +
                                        i * 32 + quad * 8);
    f32x4 acc[2][2];
#pragma unroll
    for (int j = 0; j < 2; ++j) {
        float bv = bias[c0 + j * 16 + lm];
        acc[0][j] = f32x4{bv, bv, bv, bv};
        acc[1][j] = acc[0][j];
    }
#pragma unroll
    for (int j = 0; j < 2; ++j) {
        const u16* wp = Wt + (size_t)(c0 + j * 16 + lm) * 256 + quad * 8;
#pragma unroll
        for (int i = 0; i < 8; ++i) {
            short8 bf = *(const short8*)(wp + i * 32);
#pragma unroll
            for (int s = 0; s < 2; ++s)
                acc[s][j] = __builtin_amdgcn_mfma_f32_16x16x32_bf16(af[s][i], bf,
                                                                    acc[s][j], 0, 0, 0);
        }
    }
#pragma unroll
    for (int s = 0; s < 2; ++s)
#pragma unroll
        for (int j = 0; j < 2; ++j) {
            int n = c0 + j * 16 + lm;
#pragma unroll
            for (int r = 0; r < 4; ++r) {
                int row = row0 + s * 16 + quad * 4 + r;
                float v = acc[s][j][r];
                if (EPI == 3) v *= scale;
                if (EPI == 2) v = src2[(size_t)row * 256 + n] - v;
                if (OUT == 0) out[(size_t)row * 256 + n] = v;
                else out16[(size_t)row * 256 + n] = bf16r(v);
            }
        }
}

// ---- phiQ1: out[2048,256] = relu([S_QP|S_SM][M,512] @ Wt^T + bias), fp32 A.
__global__ __launch_bounds__(256) void mgemm_f32a(const float* __restrict__ A1,
                                                  const float* __restrict__ A2,
                                                  const u16* __restrict__ Wt,
                                                  const float* __restrict__ bias,
                                                  u16* __restrict__ out16) {
    const int wv = threadIdx.x >> 6, lane = threadIdx.x & 63;
    const int lm = lane & 15, quad = lane >> 4;
    const int row0 = (blockIdx.x >> 1) * 16;
    const int c0 = (blockIdx.x & 1) * 128 + wv * 32;
    short8 af[16];
#pragma unroll
    for (int i = 0; i < 16; ++i) {
        const float* src = (i < 8)
            ? (A1 + (size_t)(row0 + lm) * 256 + i * 32 + quad * 8)
            : (A2 + (size_t)(row0 + lm) * 256 + (i - 8) * 32 + quad * 8);
        float4 f0 = *(const float4*)src;
        float4 f1 = *(const float4*)(src + 4);
        short8 t;
        t[0] = (short)bf16r(f0.x); t[1] = (short)bf16r(f0.y);
        t[2] = (short)bf16r(f0.z); t[3] = (short)bf16r(f0.w);
        t[4] = (short)bf16r(f1.x); t[5] = (short)bf16r(f1.y);
        t[6] = (short)bf16r(f1.z); t[7] = (short)bf16r(f1.w);
        af[i] = t;
    }
#pragma unroll
    for (int j = 0; j < 2; ++j) {
        int n = c0 + j * 16 + lm;
        float bv = bias[n];
        f32x4 acc = {bv, bv, bv, bv};
        const u16* wp = Wt + (size_t)n * 512 + quad * 8;
#pragma unroll
        for (int i = 0; i < 16; ++i) {
            short8 bf = *(const short8*)(wp + i * 32);
            acc = __builtin_amdgcn_mfma_f32_16x16x32_bf16(af[i], bf, acc, 0, 0, 0);
        }
#pragma unroll
        for (int r = 0; r < 4; ++r) {
            int row = row0 + quad * 4 + r;
            out16[(size_t)row * 256 + n] = bf16r(fmaxf(acc[r], 0.f));
        }
    }
}

// ---- fused qp-conv + K + V projections (A fragments loaded once).
// Block = 16 rows, 4 waves x 64 cols. qp: relu + [256->2] + entropy epi.
// K -> kmb bf16 row-major; V -> vtb bf16 head-transposed, kv-permuted.
__global__ __launch_bounds__(256) void gemm_fq(
    const u16* __restrict__ A, const u16* __restrict__ Wqp,
    const u16* __restrict__ Wk, const u16* __restrict__ Wv,
    const float* __restrict__ sb, const float* __restrict__ qpW2,
    const float* __restrict__ qpb2, const float* __restrict__ P,
    const float* __restrict__ bk, const float* __restrict__ bv,
    float* __restrict__ outPhat, float* __restrict__ outV,
    float* __restrict__ Vw2, u16* __restrict__ kmb, u16* __restrict__ vtb) {
    __shared__ float red[4][16][2];
    const int wv = threadIdx.x >> 6, lane = threadIdx.x & 63;
    const int lm = lane & 15, quad = lane >> 4;
    const int row0 = blockIdx.x * 16;
    const int b = row0 >> 12;
    short8 af[8];
#pragma unroll
    for (int i = 0; i < 8; ++i)
        af[i] = *(const short8*)(A + (size_t)(row0 + lm) * 256 + i * 32 + quad * 8);
    // --- qp part
    float c0p[4] = {0.f, 0.f, 0.f, 0.f}, c1p[4] = {0.f, 0.f, 0.f, 0.f};
#pragma unroll
    for (int j = 0; j < 4; ++j) {
        int n = wv * 64 + j * 16 + lm;
        float bv2 = sb[b * 256 + n];
        f32x4 acc = {bv2, bv2, bv2, bv2};
        const u16* wp = Wqp + (size_t)n * 256 + quad * 8;
#pragma unroll
        for (int i = 0; i < 8; ++i) {
            short8 bf = *(const short8*)(wp + i * 32);
            acc = __builtin_amdgcn_mfma_f32_16x16x32_bf16(af[i], bf, acc, 0, 0, 0);
        }
        float w20 = qpW2[n * 2], w21 = qpW2[n * 2 + 1];
#pragma unroll
        for (int r = 0; r < 4; ++r) {
            float hh = fmaxf(acc[r], 0.f);
            c0p[r] += hh * w20;
            c1p[r] += hh * w21;
        }
    }
#pragma unroll
    for (int m = 1; m < 16; m <<= 1) {
#pragma unroll
        for (int r = 0; r < 4; ++r) {
            c0p[r] += __shfl_xor(c0p[r], m);
            c1p[r] += __shfl_xor(c1p[r], m);
        }
    }
    if (lm == 0) {
#pragma unroll
        for (int r = 0; r < 4; ++r) {
            red[wv][quad * 4 + r][0] = c0p[r];
            red[wv][quad * 4 + r][1] = c1p[r];
        }
    }
    __syncthreads();
    int t = threadIdx.x;
    if (t < 16) {
        float ph0 = red[0][t][0] + red[1][t][0] + red[2][t][0] + red[3][t][0] + qpb2[0];
        float ph1 = red[0][t][1] + red[1][t][1] + red[2][t][1] + red[3][t][1] + qpb2[1];
        int hw = (row0 + t) & 4095;
        float Vv = ent2(ph0, ph1) -
                   ent2(P[(size_t)b * 8192 + hw], P[(size_t)b * 8192 + 4096 + hw]);
        outPhat[(size_t)b * 8192 + hw] = ph0;
        outPhat[(size_t)b * 8192 + 4096 + hw] = ph1;
        outV[b * 4096 + hw] = Vv;
        Vw2[b * 4096 + hw] = Vv * LOG2E;
    }
    // --- K part
#pragma unroll
    for (int j = 0; j < 4; ++j) {
        int n = wv * 64 + j * 16 + lm;
        float bv2 = bk[n];
        f32x4 acc = {bv2, bv2, bv2, bv2};
        const u16* wp = Wk + (size_t)n * 256 + quad * 8;
#pragma unroll
        for (int i = 0; i < 8; ++i) {
            short8 bf = *(const short8*)(wp + i * 32);
            acc = __builtin_amdgcn_mfma_f32_16x16x32_bf16(af[i], bf, acc, 0, 0, 0);
        }
#pragma unroll
        for (int r = 0; r < 4; ++r)
            kmb[(size_t)(row0 + quad * 4 + r) * 256 + n] = bf16r(acc[r]);
    }
    // --- V part
#pragma unroll
    for (int j = 0; j < 4; ++j) {
        int n = wv * 64 + j * 16 + lm;
        float bv2 = bv[n];
        f32x4 acc = {bv2, bv2, bv2, bv2};
        const u16* wp = Wv + (size_t)n * 256 + quad * 8;
#pragma unroll
        for (int i = 0; i < 8; ++i) {
            short8 bf = *(const short8*)(wp + i * 32);
            acc = __builtin_amdgcn_mfma_f32_16x16x32_bf16(af[i], bf, acc, 0, 0, 0);
        }
#pragma unroll
        for (int r = 0; r < 4; ++r) {
            int row = row0 + quad * 4 + r;
            int l = row & 4095;
            int pos = (l & ~63) + ((l & 15) << 2) + ((l >> 4) & 3);
            vtb[((size_t)((b * 8 + (n >> 5)) * 32 + (n & 31))) * HW + pos] = bf16r(acc[r]);
        }
    }
}

// ---- MFMA flash attention: kv-split x8, LDS-staged K/V (global_load_lds,
// triple buffer, 1 barrier/chunk), blk%8==h XCD swizzle, base-2 softmax,
// row-sum via MFMA-with-ones, V LDS segments rotated (bank-optimal).
__global__ __launch_bounds__(256) void attn_mfma(const u16* __restrict__ qm,
                                                 const u16* __restrict__ km,
                                                 const u16* __restrict__ vt,
                                                 const float* __restrict__ vb2,
                                                 u16* __restrict__ Op,
                                                 float* __restrict__ Mp,
                                                 float* __restrict__ Lp) {
    __shared__ __align__(16) u16 Kst[3][2048];   // [buf][64 kv][32 d]
    __shared__ __align__(16) u16 Vst[3][2048];   // [buf][32 d][64 u] seg-rotated
    __shared__ __align__(16) u16 p_s[4][16][80];
    const int blk = blockIdx.x;
    const int h = blk & 7, sp = (blk >> 3) & 7, qt = (blk >> 6) & 15, b = blk >> 10;
    const int tid = threadIdx.x;
    const int wv = tid >> 6, lane = tid & 63;
    const int lm = lane & 15, quad = lane >> 4;
    const int q0 = qt * 64 + wv * 16;
    const short8 qf =
        *(const short8*)(qm + ((size_t)(b * LQ + q0 + lm)) * 256 + h * 32 + quad * 8);
    const u16* kbh = km + (size_t)b * HW * 256 + h * 32;
    const u16* vbh = vt + (size_t)(b * 8 + h) * 32 * HW;
    const float* vbb = vb2 + b * HW;
    const int krow = tid >> 2, kseg = tid & 3;
    const int vd = tid >> 3, vp = tid & 7, vs = (vp - vd) & 7;
    const int kv_lo = sp * 512;
    const short os = (short)0x3F80;
    const short8 ones = {os, os, os, os, os, os, os, os};
    const f32x4 z4 = {0.f, 0.f, 0.f, 0.f};
    f32x4 o0v = z4, o1v = z4;
    float mr[4] = {-INFINITY, -INFINITY, -INFINITY, -INFINITY};
    float lr[4] = {0.f, 0.f, 0.f, 0.f};
    // prologue: stage chunks 0,1
    glds16(kbh + (size_t)(kv_lo + krow) * 256 + kseg * 8, &Kst[0][wv * 512]);
    glds16(vbh + (size_t)vd * HW + kv_lo + vs * 8, &Vst[0][wv * 512]);
    glds16(kbh + (size_t)(kv_lo + 64 + krow) * 256 + kseg * 8, &Kst[1][wv * 512]);
    glds16(vbh + (size_t)vd * HW + kv_lo + 64 + vs * 8, &Vst[1][wv * 512]);
    for (int c = 0; c < 8; ++c) {
        __syncthreads();  // buf[c] ready; drains prior-iter prefetch
        if (c + 2 < 8) {  // prefetch AFTER barrier -> drained only next iter
            int kc2 = kv_lo + (c + 2) * 64, ib = (c + 2) % 3;
            glds16(kbh + (size_t)(kc2 + krow) * 256 + kseg * 8, &Kst[ib][wv * 512]);
            glds16(vbh + (size_t)vd * HW + kc2 + vs * 8, &Vst[ib][wv * 512]);
        }
        const int idx = c % 3;
        const int kc = kv_lo + c * 64;
        const u16* kbuf = Kst[idx];
        const u16* vbuf = Vst[idx];
        f32x4 st[4];
        float vbf[4];
#pragma unroll
        for (int t = 0; t < 4; ++t) {
            short8 kf = *(const short8*)(kbuf + (t * 16 + lm) * 32 + quad * 8);
            st[t] = __builtin_amdgcn_mfma_f32_16x16x32_bf16(qf, kf, z4, 0, 0, 0);
            vbf[t] = vbb[kc + t * 16 + lm];
        }
        float al[4];
#pragma unroll
        for (int r = 0; r < 4; ++r) {
            float z0 = st[0][r] + vbf[0], z1 = st[1][r] + vbf[1];
            float z2 = st[2][r] + vbf[2], z3 = st[3][r] + vbf[3];
            float rm = fmaxf(fmaxf(z0, z1), fmaxf(z2, z3));
            rm = fmaxf(rm, __shfl_xor(rm, 1));
            rm = fmaxf(rm, __shfl_xor(rm, 2));
            rm = fmaxf(rm, __shfl_xor(rm, 4));
            rm = fmaxf(rm, __shfl_xor(rm, 8));
            float mn = fmaxf(mr[r], rm);
            al[r] = __builtin_amdgcn_exp2f(mr[r] - mn);
            mr[r] = mn;
            float p0 = __builtin_amdgcn_exp2f(z0 - mn);
            float p1 = __builtin_amdgcn_exp2f(z1 - mn);
            float p2 = __builtin_amdgcn_exp2f(z2 - mn);
            float p3 = __builtin_amdgcn_exp2f(z3 - mn);
            ushort4 pk = {(u16)(__float_as_uint(p0) >> 16),
                          (u16)(__float_as_uint(p1) >> 16),
                          (u16)(__float_as_uint(p2) >> 16),
                          (u16)(__float_as_uint(p3) >> 16)};
            *(ushort4*)&p_s[wv][quad * 4 + r][lm * 4] = pk;  // u = lm*4 + t
        }
#pragma unroll
        for (int r = 0; r < 4; ++r) { o0v[r] *= al[r]; o1v[r] *= al[r]; }
        f32x4 rsv = z4;
#pragma unroll
        for (int hf = 0; hf < 2; ++hf) {
            short8 pf = *(const short8*)&p_s[wv][lm][hf * 32 + quad * 8];
            rsv = __builtin_amdgcn_mfma_f32_16x16x32_bf16(pf, ones, rsv, 0, 0, 0);
            int ss = (hf * 4 + quad + lm) & 7;
            short8 vf0 = *(const short8*)(vbuf + lm * 64 + ss * 8);
            short8 vf1 = *(const short8*)(vbuf + (16 + lm) * 64 + ss * 8);
            o0v = __builtin_amdgcn_mfma_f32_16x16x32_bf16(pf, vf0, o0v, 0, 0, 0);
            o1v = __builtin_amdgcn_mfma_f32_16x16x32_bf16(pf, vf1, o1v, 0, 0, 0);
        }
#pragma unroll
        for (int r = 0; r < 4; ++r) lr[r] = lr[r] * al[r] + rsv[r];
    }
    const int rowb = (b * 8 + h) * LQ + q0 + quad * 4;
#pragma unroll
    for (int r = 0; r < 4; ++r) {
        size_t ro = ((size_t)sp * 16384 + rowb + r) * 32;
        Op[ro + lm] = bf16r(o0v[r]);
        Op[ro + 16 + lm] = bf16r(o1v[r]);
        if (lm == 0) {
            Mp[(size_t)sp * 16384 + rowb + r] = mr[r];
            Lp[(size_t)sp * 16384 + rowb + r] = lr[r];
        }
    }
}

// ---- combine 8 kv-splits -> aob [b,q,256] bf16
__global__ __launch_bounds__(256) void attn_combine(const u16* __restrict__ Op,
                                                    const float* __restrict__ Mp,
                                                    const float* __restrict__ Lp,
                                                    u16* __restrict__ aob) {
    int gid = blockIdx.x * 256 + threadIdx.x;
    int row = gid >> 5, d = gid & 31;
    float m[8];
    float mm = -INFINITY;
#pragma unroll
    for (int s = 0; s < 8; ++s) {
        m[s] = Mp[s * 16384 + row];
        mm = fmaxf(mm, m[s]);
    }
    float acc = 0.f, ls = 0.f;
#pragma unroll
    for (int s = 0; s < 8; ++s) {
        float w = __builtin_amdgcn_exp2f(m[s] - mm);
        float ov = __uint_as_float((unsigned)Op[((size_t)s * 16384 + row) * 32 + d] << 16);
        acc += w * ov;
        ls += w * Lp[s * 16384 + row];
    }
    int b = row >> 13, h = (row >> 10) & 7, q = row & 1023;
    aob[((size_t)(b * LQ + q)) * 256 + h * 32 + d] = bf16r(acc / ls);
}

extern "C" void kernel_launch(void* const* d_in, const int* in_sizes, int n_in,
                              void* d_out, int out_size, void* d_ws, size_t ws_size,
                              hipStream_t stream) {
    const float* S_QP = (const float*)d_in[0];
    const float* S_SM = (const float*)d_in[1];
    const float* f_q = (const float*)d_in[2];
    const float* P = (const float*)d_in[3];
    const float* qp_W1 = (const float*)d_in[4];
    const float* qp_b1 = (const float*)d_in[5];
    const float* qp_W2 = (const float*)d_in[6];
    const float* qp_b2 = (const float*)d_in[7];
    const float* phiQ_W1 = (const float*)d_in[8];
    const float* phiQ_b1 = (const float*)d_in[9];
    const float* phiQ_W2 = (const float*)d_in[10];
    const float* phiQ_b2 = (const float*)d_in[11];
    const float* Wq = (const float*)d_in[12];
    const float* bq = (const float*)d_in[13];
    const float* Wk = (const float*)d_in[14];
    const float* bk = (const float*)d_in[15];
    const float* Wv = (const float*)d_in[16];
    const float* bv = (const float*)d_in[17];
    const float* Wo = (const float*)d_in[18];
    const float* bo = (const float*)d_in[19];
    const float* phi_W = (const float*)d_in[20];
    const float* phi_b = (const float*)d_in[21];

    float* out = (float*)d_out;
    float* outS = out;            // [2,1024,256]
    float* outP = out + 524288;   // [2,2,64,64]
    float* outV = out + 540672;   // [2,1,64,64]

    float* smean = (float*)d_ws;           // 512
    float* zbias = smean + 512;            // 512 (zeros)
    float* sb = zbias + 512;               // 512
    float* Vw2 = sb + 512;                 // 8192
    float* Mp = Vw2 + 8192;                // 131072
    float* Lp = Mp + 131072;               // 131072
    float* bf1 = Lp + 131072;              // 256
    float* bf2 = bf1 + 256;                // 256
    u16* qpW1loT = (u16*)(bf2 + 256);      // 65536
    u16* WkT = qpW1loT + 65536;
    u16* WvT = WkT + 65536;
    u16* phiQ1T = WvT + 65536;             // 131072 (256x512)
    u16* WqT = phiQ1T + 131072;
    u16* phiWT = WqT + 65536;
    u16* phiQ2s = phiWT + 65536;           // straight bf16
    u16* Wos = phiQ2s + 65536;
    u16* Wf1T = Wos + 65536;               // fused phiQ_W2@Wq, Wt layout
    u16* Wf2T = Wf1T + 65536;              // fused Wo@phi_W
    u16* fqT16 = Wf2T + 65536;             // 2097152
    u16* Qmid = fqT16 + 2097152;           // 524288
    u16* qmb = Qmid + 524288;              // 524288
    u16* kmb = qmb + 524288;               // 2097152
    u16* vtb = kmb + 2097152;              // 2097152
    u16* Op16 = vtb + 2097152;             // 4194304
    u16* aob = Op16 + 4194304;             // 524288

    const float qscale = 0.17677669529663687f * LOG2E;

    hipMemsetAsync(smean, 0, 1024 * sizeof(float), stream);  // smean + zbias
    mean_kernel<<<32, 256, 0, stream>>>(S_SM, smean);
    sbias_kernel<<<2, 256, 0, stream>>>(smean, qp_W1, qp_b1, sb);
    prep_weights<<<576, 256, 0, stream>>>(qp_W1 + 65536, Wk, Wv, phiQ_W1, Wq, phi_W,
                                          phiQ_W2, Wo, qpW1loT, WkT, WvT, phiQ1T,
                                          WqT, phiWT, phiQ2s, Wos);
    bias_fuse<<<2, 256, 0, stream>>>(phiQ_b2, Wq, bq, bo, phi_W, phi_b, bf1, bf2);
    // Wf1T[n][c] = sum_o Wq[o][n]*phiQ_W2[c][o] ; Wf2T[n][d] = sum_o phiW[o][n]*Wo[d][o]
    mgemm<0, 1><<<16, 256, 0, stream>>>(WqT, phiQ2s, zbias, nullptr, 0.f, nullptr, Wf1T);
    mgemm<0, 1><<<16, 256, 0, stream>>>(phiWT, Wos, zbias, nullptr, 0.f, nullptr, Wf2T);
    transpose_fq<<<dim3(128, 8, 2), 256, 0, stream>>>(f_q, fqT16);
    gemm_fq<<<512, 256, 0, stream>>>(fqT16, qpW1loT, WkT, WvT, sb, qp_W2, qp_b2, P,
                                     bk, bv, outP, outV, Vw2, kmb, vtb);
    mgemm_f32a<<<256, 256, 0, stream>>>(S_QP, S_SM, phiQ1T, phiQ_b1, Qmid);
    mgemm<3, 1><<<128, 256, 0, stream>>>(Qmid, Wf1T, bf1, nullptr, qscale, nullptr, qmb);
    attn_mfma<<<2048, 256, 0, stream>>>(qmb, kmb, vtb, Vw2, Op16, Mp, Lp);
    attn_combine<<<2048, 256, 0, stream>>>(Op16, Mp, Lp, aob);
    mgemm<2, 0><<<128, 256, 0, stream>>>(aob, Wf2T, bf2, S_SM, 0.f, outS, nullptr);
}

// Round 5
// 201.199 us; speedup vs baseline: 3.2563x; 1.1321x over previous
//
#include <hip/hip_runtime.h>
#include <math.h>

// B=2, Lq=1024, C=256, H=W=64 -> Lk=4096, NC=2, NH=8, D=32.
// R5: launch-chain collapse. 15 dispatches -> 6 via block-range fusion:
//   K1 prep   : weight transposes + bias_fuse + mean + f_q transpose
//   K2 mid    : sbias + 2 weight-fusion GEMMs + phiQ1 (fp32-A GEMM)
//   K3 proj   : fused qp+K+V GEMM + q projection GEMM
//   K4 attn   : LDS-staged flash attention (kv-split x8)
//   K5 combine: split combine (ushort4)
//   K6 out    : final fused GEMM (S_SM - ao@Wf2 + bf2)

#define LQ 1024
#define HW 4096
#define LOG2E 1.4426950408889634f

typedef __attribute__((ext_vector_type(8))) short short8;
typedef __attribute__((ext_vector_type(4))) float f32x4;
typedef unsigned short u16;

__device__ __forceinline__ u16 bf16r(float x) {
    unsigned int u = __float_as_uint(x);
    u = (u + 0x7FFFu + ((u >> 16) & 1u)) >> 16;
    return (u16)u;
}

__device__ __forceinline__ float ent2(float a, float b) {
    float m  = fmaxf(a, b);
    float e0 = expf(a - m), e1 = expf(b - m);
    float iz = 1.f / (e0 + e1);
    float p0 = fmaxf(e0 * iz, 1e-8f);
    float p1 = fmaxf(e1 * iz, 1e-8f);
    return -(p0 * logf(p0) + p1 * logf(p1));
}

typedef __attribute__((address_space(1))) const unsigned int gas_u32;
typedef __attribute__((address_space(3))) unsigned int las_u32;
__device__ __forceinline__ void glds16(const void* g, void* l) {
    __builtin_amdgcn_global_load_lds((gas_u32*)g, (las_u32*)l, 16, 0, 0);
}

// ---- device MFMA GEMM core: out[M,256] = epi(A[M,256] @ Wt^T + bias)
// EPI: 0 none, 2 src2-r, 3 *scale. OUT: 0 f32, 1 bf16.
template <int EPI, int OUT>
__device__ __forceinline__ void mgemm_dev(int bid, const u16* __restrict__ A,
                                          const u16* __restrict__ Wt,
                                          const float* __restrict__ bias,
                                          const float* __restrict__ src2,
                                          float scale, float* __restrict__ out,
                                          u16* __restrict__ out16) {
    const int wv = threadIdx.x >> 6, lane = threadIdx.x & 63;
    const int lm = lane & 15, quad = lane >> 4;
    const int row0 = (bid >> 1) * 32;
    const int c0 = (bid & 1) * 128 + wv * 32;
    short8 af[2][8];
#pragma unroll
    for (int s = 0; s < 2; ++s)
#pragma unroll
        for (int i = 0; i < 8; ++i)
            af[s][i] = *(const short8*)(A + (size_t)(row0 + s * 16 + lm) * 256 +
                                        i * 32 + quad * 8);
    f32x4 acc[2][2];
#pragma unroll
    for (int j = 0; j < 2; ++j) {
        float bv = bias[c0 + j * 16 + lm];
        acc[0][j] = f32x4{bv, bv, bv, bv};
        acc[1][j] = acc[0][j];
    }
#pragma unroll
    for (int j = 0; j < 2; ++j) {
        const u16* wp = Wt + (size_t)(c0 + j * 16 + lm) * 256 + quad * 8;
#pragma unroll
        for (int i = 0; i < 8; ++i) {
            short8 bf = *(const short8*)(wp + i * 32);
#pragma unroll
            for (int s = 0; s < 2; ++s)
                acc[s][j] = __builtin_amdgcn_mfma_f32_16x16x32_bf16(af[s][i], bf,
                                                                    acc[s][j], 0, 0, 0);
        }
    }
#pragma unroll
    for (int s = 0; s < 2; ++s)
#pragma unroll
        for (int j = 0; j < 2; ++j) {
            int n = c0 + j * 16 + lm;
#pragma unroll
            for (int r = 0; r < 4; ++r) {
                int row = row0 + s * 16 + quad * 4 + r;
                float v = acc[s][j][r];
                if (EPI == 3) v *= scale;
                if (EPI == 2) v = src2[(size_t)row * 256 + n] - v;
                if (OUT == 0) out[(size_t)row * 256 + n] = v;
                else out16[(size_t)row * 256 + n] = bf16r(v);
            }
        }
}

// ======== K1: prep (weights transpose/convert + bias_fuse + mean + f_q transpose)
// blocks: [0,576) weights, [576,578) bias_fuse, [578,610) mean, [610,2658) fqT
__global__ __launch_bounds__(256) void k1_prep(
    const float* qpW1hi, const float* Wk, const float* Wv, const float* phiQ1,
    const float* Wq, const float* phiW, const float* phiQ2, const float* Wo,
    u16* qpW1loT, u16* WkT, u16* WvT, u16* phiQ1T, u16* WqT, u16* phiWT,
    u16* phiQ2s, u16* Wos,
    const float* pb2, const float* bq, const float* bo, const float* phib,
    float* bf1, float* bf2,
    const float* S_SM, float* smean,
    const float* f_q, u16* fqT) {
    __shared__ float tile[32][33];
    int bid = blockIdx.x;
    if (bid < 576) {
        if (bid >= 448) {  // straight bf16 converts of phiQ2, Wo
            int b2 = bid - 448;
            const float* S = (b2 < 64) ? phiQ2 : Wo;
            u16* D = (b2 < 64) ? phiQ2s : Wos;
            int idx = ((b2 & 63) * 256 + threadIdx.x) * 4;
            float4 v = *(const float4*)&S[idx];
            ushort4 pk = {bf16r(v.x), bf16r(v.y), bf16r(v.z), bf16r(v.w)};
            *(ushort4*)&D[idx] = pk;
            return;
        }
        const float* S; u16* D; int K;
        if (bid < 64)       { S = qpW1hi; D = qpW1loT; K = 256; }
        else if (bid < 128) { S = Wk; D = WkT; K = 256; bid -= 64; }
        else if (bid < 192) { S = Wv; D = WvT; K = 256; bid -= 128; }
        else if (bid < 320) { S = phiQ1; D = phiQ1T; K = 512; bid -= 192; }
        else if (bid < 384) { S = Wq; D = WqT; K = 256; bid -= 320; }
        else                { S = phiW; D = phiWT; K = 256; bid -= 384; }
        int KT = K >> 5;
        int tk = bid % KT, tn = bid / KT;
        int cc = threadIdx.x & 31, rb = threadIdx.x >> 5;
#pragma unroll
        for (int i = 0; i < 4; ++i) {
            int rr = rb + i * 8;
            tile[rr][cc] = S[(size_t)(tk * 32 + rr) * 256 + tn * 32 + cc];
        }
        __syncthreads();
#pragma unroll
        for (int i = 0; i < 4; ++i) {
            int rr = rb + i * 8;
            D[(size_t)(tn * 32 + rr) * K + tk * 32 + cc] = bf16r(tile[cc][rr]);
        }
    } else if (bid < 578) {  // bias_fuse
        int n = threadIdx.x;
        if (bid == 576) {
            float a = bq[n];
            for (int c = 0; c < 256; ++c) a += pb2[c] * Wq[c * 256 + n];
            bf1[n] = a;
        } else {
            float a = phib[n];
            for (int c = 0; c < 256; ++c) a += bo[c] * phiW[c * 256 + n];
            bf2[n] = a;
        }
    } else if (bid < 610) {  // mean partials
        int bi = bid - 578;
        int b = bi >> 4, l0 = (bi & 15) * 64;
        int c = threadIdx.x;
        const float* p = S_SM + (size_t)b * LQ * 256 + (size_t)l0 * 256 + c;
        float acc = 0.f;
#pragma unroll 8
        for (int l = 0; l < 64; ++l) acc += p[(size_t)l * 256];
        atomicAdd(&smean[b * 256 + c], acc * (1.f / 1024.f));
    } else {  // transpose f_q -> fqT bf16
        int t2 = bid - 610;
        int b = t2 >> 10, c0 = ((t2 >> 7) & 7) * 32, l0 = (t2 & 127) * 32;
        int tl = threadIdx.x & 31, tc = threadIdx.x >> 5;
#pragma unroll
        for (int r = 0; r < 4; ++r) {
            int c = c0 + tc + r * 8;
            tile[tc + r * 8][tl] = f_q[(size_t)b * 256 * HW + (size_t)c * HW + l0 + tl];
        }
        __syncthreads();
        int tc2 = threadIdx.x & 31, tl2 = threadIdx.x >> 5;
#pragma unroll
        for (int r = 0; r < 4; ++r) {
            int l = l0 + tl2 + r * 8;
            fqT[(size_t)b * HW * 256 + (size_t)l * 256 + c0 + tc2] =
                bf16r(tile[tc2][tl2 + r * 8]);
        }
    }
}

// ======== K2: mid (sbias + Wf1T/Wf2T fusion GEMMs + phiQ1 fp32-A GEMM)
// blocks: [0,2) sbias, [2,18) Wf1T, [18,34) Wf2T, [34,290) phiQ1
__global__ __launch_bounds__(256) void k2_mid(
    const float* smean, const float* qpW1, const float* qpb1, float* sb,
    const u16* WqT, const u16* phiQ2s, const float* zbias, u16* Wf1T,
    const u16* phiWT, const u16* Wos, u16* Wf2T,
    const float* S_QP, const float* S_SM, const u16* phiQ1T,
    const float* phiQb1, u16* Qmid) {
    __shared__ float s_s[256];
    int bid = blockIdx.x;
    if (bid < 2) {  // sbias
        int b = bid, o = threadIdx.x;
        s_s[o] = smean[b * 256 + o];
        __syncthreads();
        float acc = qpb1[o];
        for (int c = 0; c < 256; ++c) acc += s_s[c] * qpW1[c * 256 + o];
        sb[b * 256 + o] = acc;
    } else if (bid < 18) {
        mgemm_dev<0, 1>(bid - 2, WqT, phiQ2s, zbias, nullptr, 0.f, nullptr, Wf1T);
    } else if (bid < 34) {
        mgemm_dev<0, 1>(bid - 18, phiWT, Wos, zbias, nullptr, 0.f, nullptr, Wf2T);
    } else {  // phiQ1: relu([S_QP|S_SM] @ phiQ1T^T + b1) -> Qmid bf16
        int b2 = bid - 34;
        const int wv = threadIdx.x >> 6, lane = threadIdx.x & 63;
        const int lm = lane & 15, quad = lane >> 4;
        const int row0 = (b2 >> 1) * 16;
        const int c0 = (b2 & 1) * 128 + wv * 32;
        short8 af[16];
#pragma unroll
        for (int i = 0; i < 16; ++i) {
            const float* src = (i < 8)
                ? (S_QP + (size_t)(row0 + lm) * 256 + i * 32 + quad * 8)
                : (S_SM + (size_t)(row0 + lm) * 256 + (i - 8) * 32 + quad * 8);
            float4 f0 = *(const float4*)src;
            float4 f1 = *(const float4*)(src + 4);
            short8 t;
            t[0] = (short)bf16r(f0.x); t[1] = (short)bf16r(f0.y);
            t[2] = (short)bf16r(f0.z); t[3] = (short)bf16r(f0.w);
            t[4] = (short)bf16r(f1.x); t[5] = (short)bf16r(f1.y);
            t[6] = (short)bf16r(f1.z); t[7] = (short)bf16r(f1.w);
            af[i] = t;
        }
#pragma unroll
        for (int j = 0; j < 2; ++j) {
            int n = c0 + j * 16 + lm;
            float bv = phiQb1[n];
            f32x4 acc = {bv, bv, bv, bv};
            const u16* wp = phiQ1T + (size_t)n * 512 + quad * 8;
#pragma unroll
            for (int i = 0; i < 16; ++i) {
                short8 bf = *(const short8*)(wp + i * 32);
                acc = __builtin_amdgcn_mfma_f32_16x16x32_bf16(af[i], bf, acc, 0, 0, 0);
            }
#pragma unroll
            for (int r = 0; r < 4; ++r) {
                int row = row0 + quad * 4 + r;
                Qmid[(size_t)row * 256 + n] = bf16r(fmaxf(acc[r], 0.f));
            }
        }
    }
}

// ======== K3: proj (fused qp+K+V GEMM [0,512) + q projection [512,640))
__global__ __launch_bounds__(256) void k3_proj(
    const u16* __restrict__ A, const u16* __restrict__ Wqp,
    const u16* __restrict__ Wk, const u16* __restrict__ Wv,
    const float* __restrict__ sb, const float* __restrict__ qpW2,
    const float* __restrict__ qpb2, const float* __restrict__ P,
    const float* __restrict__ bk, const float* __restrict__ bv,
    float* __restrict__ outPhat, float* __restrict__ outV,
    float* __restrict__ Vw2, u16* __restrict__ kmb, u16* __restrict__ vtb,
    const u16* __restrict__ Qmid, const u16* __restrict__ Wf1T,
    const float* __restrict__ bf1, float qscale, u16* __restrict__ qmb) {
    __shared__ float red[4][16][2];
    int bid = blockIdx.x;
    if (bid >= 512) {
        mgemm_dev<3, 1>(bid - 512, Qmid, Wf1T, bf1, nullptr, qscale, nullptr, qmb);
        return;
    }
    const int wv = threadIdx.x >> 6, lane = threadIdx.x & 63;
    const int lm = lane & 15, quad = lane >> 4;
    const int row0 = bid * 16;
    const int b = row0 >> 12;
    short8 af[8];
#pragma unroll
    for (int i = 0; i < 8; ++i)
        af[i] = *(const short8*)(A + (size_t)(row0 + lm) * 256 + i * 32 + quad * 8);
    // --- qp part
    float c0p[4] = {0.f, 0.f, 0.f, 0.f}, c1p[4] = {0.f, 0.f, 0.f, 0.f};
#pragma unroll
    for (int j = 0; j < 4; ++j) {
        int n = wv * 64 + j * 16 + lm;
        float bv2 = sb[b * 256 + n];
        f32x4 acc = {bv2, bv2, bv2, bv2};
        const u16* wp = Wqp + (size_t)n * 256 + quad * 8;
#pragma unroll
        for (int i = 0; i < 8; ++i) {
            short8 bf = *(const short8*)(wp + i * 32);
            acc = __builtin_amdgcn_mfma_f32_16x16x32_bf16(af[i], bf, acc, 0, 0, 0);
        }
        float w20 = qpW2[n * 2], w21 = qpW2[n * 2 + 1];
#pragma unroll
        for (int r = 0; r < 4; ++r) {
            float hh = fmaxf(acc[r], 0.f);
            c0p[r] += hh * w20;
            c1p[r] += hh * w21;
        }
    }
#pragma unroll
    for (int m = 1; m < 16; m <<= 1) {
#pragma unroll
        for (int r = 0; r < 4; ++r) {
            c0p[r] += __shfl_xor(c0p[r], m);
            c1p[r] += __shfl_xor(c1p[r], m);
        }
    }
    if (lm == 0) {
#pragma unroll
        for (int r = 0; r < 4; ++r) {
            red[wv][quad * 4 + r][0] = c0p[r];
            red[wv][quad * 4 + r][1] = c1p[r];
        }
    }
    __syncthreads();
    int t = threadIdx.x;
    if (t < 16) {
        float ph0 = red[0][t][0] + red[1][t][0] + red[2][t][0] + red[3][t][0] + qpb2[0];
        float ph1 = red[0][t][1] + red[1][t][1] + red[2][t][1] + red[3][t][1] + qpb2[1];
        int hw = (row0 + t) & 4095;
        float Vv = ent2(ph0, ph1) -
                   ent2(P[(size_t)b * 8192 + hw], P[(size_t)b * 8192 + 4096 + hw]);
        outPhat[(size_t)b * 8192 + hw] = ph0;
        outPhat[(size_t)b * 8192 + 4096 + hw] = ph1;
        outV[b * 4096 + hw] = Vv;
        Vw2[b * 4096 + hw] = Vv * LOG2E;
    }
    // --- K part
#pragma unroll
    for (int j = 0; j < 4; ++j) {
        int n = wv * 64 + j * 16 + lm;
        float bv2 = bk[n];
        f32x4 acc = {bv2, bv2, bv2, bv2};
        const u16* wp = Wk + (size_t)n * 256 + quad * 8;
#pragma unroll
        for (int i = 0; i < 8; ++i) {
            short8 bf = *(const short8*)(wp + i * 32);
            acc = __builtin_amdgcn_mfma_f32_16x16x32_bf16(af[i], bf, acc, 0, 0, 0);
        }
#pragma unroll
        for (int r = 0; r < 4; ++r)
            kmb[(size_t)(row0 + quad * 4 + r) * 256 + n] = bf16r(acc[r]);
    }
    // --- V part
#pragma unroll
    for (int j = 0; j < 4; ++j) {
        int n = wv * 64 + j * 16 + lm;
        float bv2 = bv[n];
        f32x4 acc = {bv2, bv2, bv2, bv2};
        const u16* wp = Wv + (size_t)n * 256 + quad * 8;
#pragma unroll
        for (int i = 0; i < 8; ++i) {
            short8 bf = *(const short8*)(wp + i * 32);
            acc = __builtin_amdgcn_mfma_f32_16x16x32_bf16(af[i], bf, acc, 0, 0, 0);
        }
#pragma unroll
        for (int r = 0; r < 4; ++r) {
            int row = row0 + quad * 4 + r;
            int l = row & 4095;
            int pos = (l & ~63) + ((l & 15) << 2) + ((l >> 4) & 3);
            vtb[((size_t)((b * 8 + (n >> 5)) * 32 + (n & 31))) * HW + pos] = bf16r(acc[r]);
        }
    }
}

// ======== K4: MFMA flash attention (unchanged from R4)
__global__ __launch_bounds__(256) void attn_mfma(const u16* __restrict__ qm,
                                                 const u16* __restrict__ km,
                                                 const u16* __restrict__ vt,
                                                 const float* __restrict__ vb2,
                                                 u16* __restrict__ Op,
                                                 float* __restrict__ Mp,
                                                 float* __restrict__ Lp) {
    __shared__ __align__(16) u16 Kst[3][2048];
    __shared__ __align__(16) u16 Vst[3][2048];
    __shared__ __align__(16) u16 p_s[4][16][80];
    const int blk = blockIdx.x;
    const int h = blk & 7, sp = (blk >> 3) & 7, qt = (blk >> 6) & 15, b = blk >> 10;
    const int tid = threadIdx.x;
    const int wv = tid >> 6, lane = tid & 63;
    const int lm = lane & 15, quad = lane >> 4;
    const int q0 = qt * 64 + wv * 16;
    const short8 qf =
        *(const short8*)(qm + ((size_t)(b * LQ + q0 + lm)) * 256 + h * 32 + quad * 8);
    const u16* kbh = km + (size_t)b * HW * 256 + h * 32;
    const u16* vbh = vt + (size_t)(b * 8 + h) * 32 * HW;
    const float* vbb = vb2 + b * HW;
    const int krow = tid >> 2, kseg = tid & 3;
    const int vd = tid >> 3, vp = tid & 7, vs = (vp - vd) & 7;
    const int kv_lo = sp * 512;
    const short os = (short)0x3F80;
    const short8 ones = {os, os, os, os, os, os, os, os};
    const f32x4 z4 = {0.f, 0.f, 0.f, 0.f};
    f32x4 o0v = z4, o1v = z4;
    float mr[4] = {-INFINITY, -INFINITY, -INFINITY, -INFINITY};
    float lr[4] = {0.f, 0.f, 0.f, 0.f};
    glds16(kbh + (size_t)(kv_lo + krow) * 256 + kseg * 8, &Kst[0][wv * 512]);
    glds16(vbh + (size_t)vd * HW + kv_lo + vs * 8, &Vst[0][wv * 512]);
    glds16(kbh + (size_t)(kv_lo + 64 + krow) * 256 + kseg * 8, &Kst[1][wv * 512]);
    glds16(vbh + (size_t)vd * HW + kv_lo + 64 + vs * 8, &Vst[1][wv * 512]);
    for (int c = 0; c < 8; ++c) {
        __syncthreads();
        if (c + 2 < 8) {
            int kc2 = kv_lo + (c + 2) * 64, ib = (c + 2) % 3;
            glds16(kbh + (size_t)(kc2 + krow) * 256 + kseg * 8, &Kst[ib][wv * 512]);
            glds16(vbh + (size_t)vd * HW + kc2 + vs * 8, &Vst[ib][wv * 512]);
        }
        const int idx = c % 3;
        const int kc = kv_lo + c * 64;
        const u16* kbuf = Kst[idx];
        const u16* vbuf = Vst[idx];
        f32x4 st[4];
        float vbf[4];
#pragma unroll
        for (int t = 0; t < 4; ++t) {
            short8 kf = *(const short8*)(kbuf + (t * 16 + lm) * 32 + quad * 8);
            st[t] = __builtin_amdgcn_mfma_f32_16x16x32_bf16(qf, kf, z4, 0, 0, 0);
            vbf[t] = vbb[kc + t * 16 + lm];
        }
        float al[4];
#pragma unroll
        for (int r = 0; r < 4; ++r) {
            float z0 = st[0][r] + vbf[0], z1 = st[1][r] + vbf[1];
            float z2 = st[2][r] + vbf[2], z3 = st[3][r] + vbf[3];
            float rm = fmaxf(fmaxf(z0, z1), fmaxf(z2, z3));
            rm = fmaxf(rm, __shfl_xor(rm, 1));
            rm = fmaxf(rm, __shfl_xor(rm, 2));
            rm = fmaxf(rm, __shfl_xor(rm, 4));
            rm = fmaxf(rm, __shfl_xor(rm, 8));
            float mn = fmaxf(mr[r], rm);
            al[r] = __builtin_amdgcn_exp2f(mr[r] - mn);
            mr[r] = mn;
            float p0 = __builtin_amdgcn_exp2f(z0 - mn);
            float p1 = __builtin_amdgcn_exp2f(z1 - mn);
            float p2 = __builtin_amdgcn_exp2f(z2 - mn);
            float p3 = __builtin_amdgcn_exp2f(z3 - mn);
            ushort4 pk = {(u16)(__float_as_uint(p0) >> 16),
                          (u16)(__float_as_uint(p1) >> 16),
                          (u16)(__float_as_uint(p2) >> 16),
                          (u16)(__float_as_uint(p3) >> 16)};
            *(ushort4*)&p_s[wv][quad * 4 + r][lm * 4] = pk;
        }
#pragma unroll
        for (int r = 0; r < 4; ++r) { o0v[r] *= al[r]; o1v[r] *= al[r]; }
        f32x4 rsv = z4;
#pragma unroll
        for (int hf = 0; hf < 2; ++hf) {
            short8 pf = *(const short8*)&p_s[wv][lm][hf * 32 + quad * 8];
            rsv = __builtin_amdgcn_mfma_f32_16x16x32_bf16(pf, ones, rsv, 0, 0, 0);
            int ss = (hf * 4 + quad + lm) & 7;
            short8 vf0 = *(const short8*)(vbuf + lm * 64 + ss * 8);
            short8 vf1 = *(const short8*)(vbuf + (16 + lm) * 64 + ss * 8);
            o0v = __builtin_amdgcn_mfma_f32_16x16x32_bf16(pf, vf0, o0v, 0, 0, 0);
            o1v = __builtin_amdgcn_mfma_f32_16x16x32_bf16(pf, vf1, o1v, 0, 0, 0);
        }
#pragma unroll
        for (int r = 0; r < 4; ++r) lr[r] = lr[r] * al[r] + rsv[r];
    }
    const int rowb = (b * 8 + h) * LQ + q0 + quad * 4;
#pragma unroll
    for (int r = 0; r < 4; ++r) {
        size_t ro = ((size_t)sp * 16384 + rowb + r) * 32;
        Op[ro + lm] = bf16r(o0v[r]);
        Op[ro + 16 + lm] = bf16r(o1v[r]);
        if (lm == 0) {
            Mp[(size_t)sp * 16384 + rowb + r] = mr[r];
            Lp[(size_t)sp * 16384 + rowb + r] = lr[r];
        }
    }
}

// ======== K5: combine 8 kv-splits -> aob bf16 (ushort4 per thread)
__global__ __launch_bounds__(256) void attn_combine(const u16* __restrict__ Op,
                                                    const float* __restrict__ Mp,
                                                    const float* __restrict__ Lp,
                                                    u16* __restrict__ aob) {
    int idx = blockIdx.x * 256 + threadIdx.x;  // 131072 = 16384 rows * 8 dgroups
    int row = idx >> 3, d0 = (idx & 7) * 4;
    float m[8];
    float mm = -INFINITY;
#pragma unroll
    for (int s = 0; s < 8; ++s) {
        m[s] = Mp[s * 16384 + row];
        mm = fmaxf(mm, m[s]);
    }
    float a0 = 0.f, a1 = 0.f, a2 = 0.f, a3 = 0.f, ls = 0.f;
#pragma unroll
    for (int s = 0; s < 8; ++s) {
        float w = __builtin_amdgcn_exp2f(m[s] - mm);
        ushort4 ov = *(const ushort4*)&Op[((size_t)s * 16384 + row) * 32 + d0];
        a0 += w * __uint_as_float((unsigned)ov.x << 16);
        a1 += w * __uint_as_float((unsigned)ov.y << 16);
        a2 += w * __uint_as_float((unsigned)ov.z << 16);
        a3 += w * __uint_as_float((unsigned)ov.w << 16);
        ls += w * Lp[s * 16384 + row];
    }
    float il = 1.f / ls;
    int b = row >> 13, h = (row >> 10) & 7, q = row & 1023;
    ushort4 pk = {bf16r(a0 * il), bf16r(a1 * il), bf16r(a2 * il), bf16r(a3 * il)};
    *(ushort4*)&aob[((size_t)(b * LQ + q)) * 256 + h * 32 + d0] = pk;
}

// ======== K6: final GEMM
__global__ __launch_bounds__(256) void k6_out(const u16* __restrict__ aob,
                                              const u16* __restrict__ Wf2T,
                                              const float* __restrict__ bf2,
                                              const float* __restrict__ S_SM,
                                              float* __restrict__ outS) {
    mgemm_dev<2, 0>(blockIdx.x, aob, Wf2T, bf2, S_SM, 0.f, outS, nullptr);
}

extern "C" void kernel_launch(void* const* d_in, const int* in_sizes, int n_in,
                              void* d_out, int out_size, void* d_ws, size_t ws_size,
                              hipStream_t stream) {
    const float* S_QP = (const float*)d_in[0];
    const float* S_SM = (const float*)d_in[1];
    const float* f_q = (const float*)d_in[2];
    const float* P = (const float*)d_in[3];
    const float* qp_W1 = (const float*)d_in[4];
    const float* qp_b1 = (const float*)d_in[5];
    const float* qp_W2 = (const float*)d_in[6];
    const float* qp_b2 = (const float*)d_in[7];
    const float* phiQ_W1 = (const float*)d_in[8];
    const float* phiQ_b1 = (const float*)d_in[9];
    const float* phiQ_W2 = (const float*)d_in[10];
    const float* phiQ_b2 = (const float*)d_in[11];
    const float* Wq = (const float*)d_in[12];
    const float* bq = (const float*)d_in[13];
    const float* Wk = (const float*)d_in[14];
    const float* bk = (const float*)d_in[15];
    const float* Wv = (const float*)d_in[16];
    const float* bv = (const float*)d_in[17];
    const float* Wo = (const float*)d_in[18];
    const float* bo = (const float*)d_in[19];
    const float* phi_W = (const float*)d_in[20];
    const float* phi_b = (const float*)d_in[21];

    float* out = (float*)d_out;
    float* outS = out;            // [2,1024,256]
    float* outP = out + 524288;   // [2,2,64,64]
    float* outV = out + 540672;   // [2,1,64,64]

    float* smean = (float*)d_ws;           // 512
    float* zbias = smean + 512;            // 512 (zeros)
    float* sb = zbias + 512;               // 512
    float* Vw2 = sb + 512;                 // 8192
    float* Mp = Vw2 + 8192;                // 131072
    float* Lp = Mp + 131072;               // 131072
    float* bf1 = Lp + 131072;              // 256
    float* bf2 = bf1 + 256;                // 256
    u16* qpW1loT = (u16*)(bf2 + 256);      // 65536
    u16* WkT = qpW1loT + 65536;
    u16* WvT = WkT + 65536;
    u16* phiQ1T = WvT + 65536;             // 131072 (256x512)
    u16* WqT = phiQ1T + 131072;
    u16* phiWT = WqT + 65536;
    u16* phiQ2s = phiWT + 65536;
    u16* Wos = phiQ2s + 65536;
    u16* Wf1T = Wos + 65536;
    u16* Wf2T = Wf1T + 65536;
    u16* fqT16 = Wf2T + 65536;             // 2097152
    u16* Qmid = fqT16 + 2097152;           // 524288
    u16* qmb = Qmid + 524288;              // 524288
    u16* kmb = qmb + 524288;               // 2097152
    u16* vtb = kmb + 2097152;              // 2097152
    u16* Op16 = vtb + 2097152;             // 4194304
    u16* aob = Op16 + 4194304;             // 524288

    const float qscale = 0.17677669529663687f * LOG2E;

    hipMemsetAsync(smean, 0, 1024 * sizeof(float), stream);  // smean + zbias
    k1_prep<<<2658, 256, 0, stream>>>(qp_W1 + 65536, Wk, Wv, phiQ_W1, Wq, phi_W,
                                      phiQ_W2, Wo, qpW1loT, WkT, WvT, phiQ1T, WqT,
                                      phiWT, phiQ2s, Wos, phiQ_b2, bq, bo, phi_b,
                                      bf1, bf2, S_SM, smean, f_q, fqT16);
    k2_mid<<<290, 256, 0, stream>>>(smean, qp_W1, qp_b1, sb, WqT, phiQ2s, zbias,
                                    Wf1T, phiWT, Wos, Wf2T, S_QP, S_SM, phiQ1T,
                                    phiQ_b1, Qmid);
    k3_proj<<<640, 256, 0, stream>>>(fqT16, qpW1loT, WkT, WvT, sb, qp_W2, qp_b2, P,
                                     bk, bv, outP, outV, Vw2, kmb, vtb, Qmid, Wf1T,
                                     bf1, qscale, qmb);
    attn_mfma<<<2048, 256, 0, stream>>>(qmb, kmb, vtb, Vw2, Op16, Mp, Lp);
    attn_combine<<<512, 256, 0, stream>>>(Op16, Mp, Lp, aob);
    k6_out<<<128, 256, 0, stream>>>(aob, Wf2T, bf2, S_SM, outS);
}